// Round 16
// baseline (655.154 us; speedup 1.0000x reference)
//
#include <hip/hip_runtime.h>
#include <math.h>

#define BB 32
#define LL 512
#define CHN 512
#define NHH 8
#define HDD 64

typedef __attribute__((ext_vector_type(8))) short short8;
typedef __attribute__((ext_vector_type(4))) float f32x4;

__device__ __forceinline__ float b2f(unsigned short s) {
    union { unsigned int u; float f; } c; c.u = ((unsigned int)s) << 16; return c.f;
}
__device__ __forceinline__ unsigned short f2b(float f) {
    union { float f; unsigned int u; } c; c.f = f;
    return (unsigned short)((c.u + 0x7fffu + ((c.u >> 16) & 1u)) >> 16);
}

// swizzled ushort index for a [rows][64] bf16 LDS tile (breaks 128B-stride conflicts)
#define SWZ(row, col) ((((row) * 64 + (col))) ^ (((row) & 7) << 3))

__device__ __forceinline__ void gl16(const unsigned short* g, unsigned short* l) {
    __builtin_amdgcn_global_load_lds(
        (const __attribute__((address_space(1))) unsigned int*)g,
        (__attribute__((address_space(3))) unsigned int*)l, 16, 0, 0);
}

// ---------------------------------------------------------------------------
// Weight slab (bf16 ushorts):
//   [0,524288)          qw  L0,L1
//   [524288,1572864)    KV: per layer contiguous [kw_i(512x512); vw_i(512x512)]
//   [1572864,2097152)   c1w L0,L1
//   [2097152,2621440)   c2w L0,L1
//   [2621440,3145728)   decw
// cvt7 also converts log_seqs -> R1.
// ---------------------------------------------------------------------------
__global__ __launch_bounds__(256) void cvt7_kernel(
    const float* __restrict__ p0, const float* __restrict__ p1,
    const float* __restrict__ p2, const float* __restrict__ p3,
    const float* __restrict__ p4, const float* __restrict__ p5,
    unsigned short* __restrict__ y,
    const float* __restrict__ seqs, unsigned short* __restrict__ R1)
{
    const int j = blockIdx.y;
    const int i = blockIdx.x * 256 + threadIdx.x;   // 0..131071 (float4 units)
    if (j < 6) {
        const float* x = j == 0 ? p0 : j == 1 ? p1 : j == 2 ? p2
                       : j == 3 ? p3 : j == 4 ? p4 : p5;
        const float4 v = reinterpret_cast<const float4*>(x)[i];
        ushort4 o;
        o.x = f2b(v.x); o.y = f2b(v.y); o.z = f2b(v.z); o.w = f2b(v.w);
        size_t dst4;
        if (j == 1)      dst4 = 131072 + i + (i >= 65536 ? 65536 : 0);          // kw
        else if (j == 2) dst4 = 131072 + 65536 + i + (i >= 65536 ? 65536 : 0);  // vw
        else             dst4 = (size_t)j * 131072 + i;  // qw(0), c1(3), c2(4), dec(5)
        reinterpret_cast<ushort4*>(y)[dst4] = o;
    } else {
        #pragma unroll
        for (int t = 0; t < 16; ++t) {
            const int ii = t * 131072 + i;
            const float4 v = reinterpret_cast<const float4*>(seqs)[ii];
            ushort4 o;
            o.x = f2b(v.x); o.y = f2b(v.y); o.z = f2b(v.z); o.w = f2b(v.w);
            reinterpret_cast<ushort4*>(R1)[ii] = o;
        }
    }
}

// ---------------------------------------------------------------------------
// Row LayerNorm over CH=512 (eps=1e-8), bf16 input, f32 stats.
// ---------------------------------------------------------------------------
__global__ __launch_bounds__(256) void ln_kernel(
    const unsigned short* __restrict__ x, const float* __restrict__ g,
    const float* __restrict__ b, float* __restrict__ yf,
    unsigned short* __restrict__ yb)
{
    const int row = blockIdx.x;
    const int tid = threadIdx.x;
    const size_t base = (size_t)row * CHN;
    const ushort2 v2 = *reinterpret_cast<const ushort2*>(x + base + tid * 2);
    const float vx = b2f(v2.x), vy = b2f(v2.y);
    float s  = vx + vy;
    float ss = vx * vx + vy * vy;
    #pragma unroll
    for (int m = 1; m < 64; m <<= 1) {
        s  += __shfl_xor(s, m);
        ss += __shfl_xor(ss, m);
    }
    __shared__ float red[8];
    const int wave = tid >> 6;
    if ((tid & 63) == 0) { red[wave] = s; red[4 + wave] = ss; }
    __syncthreads();
    s  = red[0] + red[1] + red[2] + red[3];
    ss = red[4] + red[5] + red[6] + red[7];
    const float mean = s * (1.0f / CHN);
    const float var  = ss * (1.0f / CHN) - mean * mean;
    const float inv  = rsqrtf(var + 1e-8f);
    const int c = tid * 2;
    float ox = (vx - mean) * inv * g[c]     + b[c];
    float oy = (vy - mean) * inv * g[c + 1] + b[c + 1];
    if (yf) *reinterpret_cast<float2*>(yf + base + c) = make_float2(ox, oy);
    if (yb) {
        ushort2 ob; ob.x = f2b(ox); ob.y = f2b(oy);
        *reinterpret_cast<ushort2*>(yb + base + c) = ob;
    }
}

// ---------------------------------------------------------------------------
// bf16 MFMA GEMM body (depth-3, r14 measured-best): 256x128 tile, BK=32,
// 8 waves (4x2). NBX = N/128 tiles. act: 0=none 1=relu 3=scale-by-0.125.
// ---------------------------------------------------------------------------
template <int NT, int NBX>
__device__ __forceinline__ void gemm_body(
    const unsigned short* __restrict__ A,
    const unsigned short* __restrict__ A2,
    const unsigned short* __restrict__ W, int ldw,
    const float* __restrict__ bias,
    const float* __restrict__ pos,
    const unsigned short* __restrict__ resb,
    float* __restrict__ outf,
    unsigned short* __restrict__ outb,
    unsigned short* __restrict__ outbt,
    int act, int bid,
    unsigned short* lA, unsigned short* lB)
{
    const int tid  = threadIdx.x;
    const int lane = tid & 63;
    const int wid  = tid >> 6;          // 0..7

    const int swz = (bid & 7) * (NBX * 8) + (bid >> 3);
    const int by = swz / NBX, bx = swz % NBX;
    const int bm = by * 256, bn = bx * 128;

    const int ia0 = wid * 2, ia1 = wid * 2 + 1;
    const int hiA0 = ia0 >> 2, rgA0 = ia0 & 3;
    const int hiA1 = ia1 >> 2, rgA1 = ia1 & 3;
    const int hiB = wid >> 1, rgB = wid & 1;

    const unsigned short* Ax = A2 ? A2 : A;
    const unsigned short* aS0  = A  + (size_t)(bm + rgA0 * 64 + lane) * 512 + hiA0 * 8;
    const unsigned short* aS1  = A  + (size_t)(bm + rgA1 * 64 + lane) * 512 + hiA1 * 8;
    const unsigned short* a2S0 = Ax + (size_t)(bm + rgA0 * 64 + lane) * 512 + hiA0 * 8;
    const unsigned short* a2S1 = Ax + (size_t)(bm + rgA1 * 64 + lane) * 512 + hiA1 * 8;
    const unsigned short* wS   = W + (size_t)(bn + rgB * 64 + lane) * ldw + hiB * 8;
    const int dA0 = (hiA0 * 256 + rgA0 * 64) * 8;
    const int dA1 = (hiA1 * 256 + rgA1 * 64) * 8;
    const int dB  = (hiB * 128 + rgB * 64) * 8;

    const int wr = wid >> 1, wc = wid & 1;
    const int fr = lane & 15;
    const int fq = lane >> 4;

    f32x4 acc[4][4];
    #pragma unroll
    for (int m = 0; m < 4; ++m)
        #pragma unroll
        for (int n = 0; n < 4; ++n)
            acc[m][n] = (f32x4){0.f, 0.f, 0.f, 0.f};

    #define MG_STAGE(buf, t)                                            \
        do {                                                            \
            const int k0 = ((t) & 15) * 32;                             \
            const unsigned short* s0 = ((t) < 16) ? aS0 : a2S0;         \
            const unsigned short* s1 = ((t) < 16) ? aS1 : a2S1;         \
            gl16(s0 + k0, &lA[(buf) * 8192 + dA0]);                     \
            gl16(s1 + k0, &lA[(buf) * 8192 + dA1]);                     \
            gl16(wS + (t) * 32, &lB[(buf) * 4096 + dB]);                \
        } while (0)

    MG_STAGE(0, 0);
    MG_STAGE(1, 1);

    #pragma unroll
    for (int t = 0; t < NT; ++t) {
        const int cur = t % 3;
        if (t + 2 < NT) {
            MG_STAGE((t + 2) % 3, t + 2);
            asm volatile("s_waitcnt vmcnt(6)" ::: "memory");
        } else if (t + 1 < NT) {
            asm volatile("s_waitcnt vmcnt(3)" ::: "memory");
        } else {
            asm volatile("s_waitcnt vmcnt(0)" ::: "memory");
        }
        __builtin_amdgcn_s_barrier();

        const unsigned short* pa = &lA[cur * 8192 + (fq * 256 + wr * 64 + fr) * 8];
        const unsigned short* pb = &lB[cur * 4096 + (fq * 128 + wc * 64 + fr) * 8];
        short8 aF[4], bF[4];
        #pragma unroll
        for (int m = 0; m < 4; ++m)
            aF[m] = *reinterpret_cast<const short8*>(pa + m * 128);
        #pragma unroll
        for (int n = 0; n < 4; ++n)
            bF[n] = *reinterpret_cast<const short8*>(pb + n * 128);
        asm volatile("s_waitcnt lgkmcnt(0)" ::: "memory");
        __builtin_amdgcn_s_barrier();

        __builtin_amdgcn_s_setprio(1);
        #pragma unroll
        for (int m = 0; m < 4; ++m)
            #pragma unroll
            for (int n = 0; n < 4; ++n)
                acc[m][n] = __builtin_amdgcn_mfma_f32_16x16x32_bf16(
                    aF[m], bF[n], acc[m][n], 0, 0, 0);
        __builtin_amdgcn_s_setprio(0);
    }
    #undef MG_STAGE

    const int row0 = bm + wr * 64, col0 = bn + wc * 64;
    #pragma unroll
    for (int m = 0; m < 4; ++m) {
        #pragma unroll
        for (int n = 0; n < 4; ++n) {
            const int col = col0 + n * 16 + fr;
            const float bia = bias ? bias[col] : 0.f;
            ushort4 o4;
            #pragma unroll
            for (int r = 0; r < 4; ++r) {
                const int row = row0 + m * 16 + fq * 4 + r;
                float v = acc[m][n][r] + bia;
                if (pos) v += pos[(size_t)(row & (LL - 1)) * CHN + col];
                if (act == 1) v = fmaxf(v, 0.f);
                else if (act == 3) v *= 0.125f;
                const size_t idx = (size_t)row * CHN + col;
                if (resb) v += b2f(resb[idx]);
                if (outf) outf[idx] = v;
                if (outb) outb[idx] = f2b(v);
                ((unsigned short*)&o4)[r] = f2b(v);
            }
            if (outbt) {
                const int rw = row0 + m * 16 + fq * 4;
                *reinterpret_cast<ushort4*>(
                    &outbt[((size_t)(rw >> 9) * 512 + col) * 512 + (rw & 511)]) = o4;
            }
        }
    }
}

// ---------------------------------------------------------------------------
// KV body: N=1024 GEMM over W_kv = [kw;vw], depth-3. Block-uniform epilogue
// split: bn<512 -> K (posK, KBb); bn>=512 -> V (posV, VTb transposed).
// ---------------------------------------------------------------------------
__device__ __forceinline__ void kv_body(
    const unsigned short* __restrict__ A,
    const unsigned short* __restrict__ Wkv,
    const float* __restrict__ kb, const float* __restrict__ vb,
    const float* __restrict__ posK, const float* __restrict__ posV,
    unsigned short* __restrict__ KBb, unsigned short* __restrict__ VTb,
    int bid, unsigned short* lA, unsigned short* lB)
{
    const int tid  = threadIdx.x;
    const int lane = tid & 63;
    const int wid  = tid >> 6;

    const int swz = (bid & 7) * 64 + (bid >> 3);   // 512 blocks
    const int by = swz >> 3, bx = swz & 7;
    const int bm = by * 256, bn = bx * 128;

    const int ia0 = wid * 2, ia1 = wid * 2 + 1;
    const int hiA0 = ia0 >> 2, rgA0 = ia0 & 3;
    const int hiA1 = ia1 >> 2, rgA1 = ia1 & 3;
    const int hiB = wid >> 1, rgB = wid & 1;

    const unsigned short* aS0 = A + (size_t)(bm + rgA0 * 64 + lane) * 512 + hiA0 * 8;
    const unsigned short* aS1 = A + (size_t)(bm + rgA1 * 64 + lane) * 512 + hiA1 * 8;
    const unsigned short* wS  = Wkv + (size_t)(bn + rgB * 64 + lane) * 512 + hiB * 8;
    const int dA0 = (hiA0 * 256 + rgA0 * 64) * 8;
    const int dA1 = (hiA1 * 256 + rgA1 * 64) * 8;
    const int dB  = (hiB * 128 + rgB * 64) * 8;

    const int wr = wid >> 1, wc = wid & 1;
    const int fr = lane & 15;
    const int fq = lane >> 4;

    f32x4 acc[4][4];
    #pragma unroll
    for (int m = 0; m < 4; ++m)
        #pragma unroll
        for (int n = 0; n < 4; ++n)
            acc[m][n] = (f32x4){0.f, 0.f, 0.f, 0.f};

    #define KV_STAGE(buf, t)                                            \
        do {                                                            \
            const int k0 = (t) * 32;                                    \
            gl16(aS0 + k0, &lA[(buf) * 8192 + dA0]);                    \
            gl16(aS1 + k0, &lA[(buf) * 8192 + dA1]);                    \
            gl16(wS + k0, &lB[(buf) * 4096 + dB]);                      \
        } while (0)

    KV_STAGE(0, 0);
    KV_STAGE(1, 1);

    #pragma unroll
    for (int t = 0; t < 16; ++t) {
        const int cur = t % 3;
        if (t + 2 < 16) {
            KV_STAGE((t + 2) % 3, t + 2);
            asm volatile("s_waitcnt vmcnt(6)" ::: "memory");
        } else if (t + 1 < 16) {
            asm volatile("s_waitcnt vmcnt(3)" ::: "memory");
        } else {
            asm volatile("s_waitcnt vmcnt(0)" ::: "memory");
        }
        __builtin_amdgcn_s_barrier();

        const unsigned short* pa = &lA[cur * 8192 + (fq * 256 + wr * 64 + fr) * 8];
        const unsigned short* pb = &lB[cur * 4096 + (fq * 128 + wc * 64 + fr) * 8];
        short8 aF[4], bF[4];
        #pragma unroll
        for (int m = 0; m < 4; ++m)
            aF[m] = *reinterpret_cast<const short8*>(pa + m * 128);
        #pragma unroll
        for (int n = 0; n < 4; ++n)
            bF[n] = *reinterpret_cast<const short8*>(pb + n * 128);
        asm volatile("s_waitcnt lgkmcnt(0)" ::: "memory");
        __builtin_amdgcn_s_barrier();

        __builtin_amdgcn_s_setprio(1);
        #pragma unroll
        for (int m = 0; m < 4; ++m)
            #pragma unroll
            for (int n = 0; n < 4; ++n)
                acc[m][n] = __builtin_amdgcn_mfma_f32_16x16x32_bf16(
                    aF[m], bF[n], acc[m][n], 0, 0, 0);
        __builtin_amdgcn_s_setprio(0);
    }
    #undef KV_STAGE

    const int row0 = bm + wr * 64;
    if (bn < 512) {
        const int col0 = bn + wc * 64;
        #pragma unroll
        for (int m = 0; m < 4; ++m) {
            #pragma unroll
            for (int n = 0; n < 4; ++n) {
                const int col = col0 + n * 16 + fr;
                const float bia = kb[col];
                #pragma unroll
                for (int r = 0; r < 4; ++r) {
                    const int row = row0 + m * 16 + fq * 4 + r;
                    float v = acc[m][n][r] + bia
                            + posK[(size_t)(row & (LL - 1)) * CHN + col];
                    KBb[(size_t)row * CHN + col] = f2b(v);
                }
            }
        }
    } else {
        const int vcol0 = (bn - 512) + wc * 64;
        #pragma unroll
        for (int m = 0; m < 4; ++m) {
            #pragma unroll
            for (int n = 0; n < 4; ++n) {
                const int vcol = vcol0 + n * 16 + fr;
                const float bia = vb[vcol];
                ushort4 o4;
                #pragma unroll
                for (int r = 0; r < 4; ++r) {
                    const int row = row0 + m * 16 + fq * 4 + r;
                    float v = acc[m][n][r] + bia
                            + posV[(size_t)(row & (LL - 1)) * CHN + vcol];
                    ((unsigned short*)&o4)[r] = f2b(v);
                }
                const int rw = row0 + m * 16 + fq * 4;
                *reinterpret_cast<ushort4*>(
                    &VTb[((size_t)(rw >> 9) * 512 + vcol) * 512 + (rw & 511)]) = o4;
            }
        }
    }
}

__global__ __launch_bounds__(512) void mgemm_kernel(
    const unsigned short* __restrict__ A,
    const unsigned short* __restrict__ W, int ldw,
    const float* __restrict__ bias,
    const float* __restrict__ pos,
    const unsigned short* __restrict__ resb,
    float* __restrict__ outf,
    unsigned short* __restrict__ outb,
    unsigned short* __restrict__ outbt,
    int act)
{
    __shared__ alignas(16) unsigned short lA[3 * 8192];
    __shared__ alignas(16) unsigned short lB[3 * 4096];
    gemm_body<16, 4>(A, nullptr, W, ldw, bias, pos, resb, outf, outb, outbt, act,
                     blockIdx.x, lA, lB);
}

// Fused Q + KV: blocks 0-255 = Q GEMM (A=qinb), 256-767 = KV GEMM (A=curb).
__global__ __launch_bounds__(512) void qkv2_kernel(
    const unsigned short* __restrict__ qinb, const unsigned short* __restrict__ curb,
    const unsigned short* __restrict__ Wq, const unsigned short* __restrict__ Wkv,
    const float* __restrict__ qb, const float* __restrict__ kb,
    const float* __restrict__ vb,
    const float* __restrict__ posK, const float* __restrict__ posV,
    unsigned short* __restrict__ QBb, unsigned short* __restrict__ KBb,
    unsigned short* __restrict__ VTb)
{
    __shared__ alignas(16) unsigned short lA[3 * 8192];
    __shared__ alignas(16) unsigned short lB[3 * 4096];
    if (blockIdx.x < 256) {
        gemm_body<16, 4>(qinb, nullptr, Wq, 512, qb, nullptr, nullptr,
                         nullptr, QBb, nullptr, 3, blockIdx.x, lA, lB);
    } else {
        kv_body(curb, Wkv, kb, vb, posK, posV, KBb, VTb, blockIdx.x - 256, lA, lB);
    }
}

// Decoder fused: dec = [log_feats | x_t] @ decw^T + decb  (K=1024, two A sources)
__global__ __launch_bounds__(512) void dec_kernel(
    const unsigned short* __restrict__ R0b, const unsigned short* __restrict__ R1b,
    const unsigned short* __restrict__ Wd, const float* __restrict__ decb,
    float* __restrict__ dec)
{
    __shared__ alignas(16) unsigned short lA[3 * 8192];
    __shared__ alignas(16) unsigned short lB[3 * 4096];
    gemm_body<32, 4>(R0b, R1b, Wd, 1024, decb, nullptr, nullptr, dec, nullptr,
                     nullptr, 0, blockIdx.x, lA, lB);
}

// ---------------------------------------------------------------------------
// Split-K small-M GEMM for the temb path.
// ---------------------------------------------------------------------------
__global__ __launch_bounds__(256) void skgemm_kernel(
    const float* __restrict__ A, int K,
    const float* __restrict__ W, int N,
    float* __restrict__ P)
{
    __shared__ float As[32][128];
    const int tid = threadIdx.x;
    const int kz  = blockIdx.y;
    const int c   = blockIdx.x * 256 + tid;

    #pragma unroll
    for (int i = 0; i < 16; ++i) {
        const int idx = i * 256 + tid;
        const int r = idx >> 7, k = idx & 127;
        As[r][k] = A[(size_t)r * K + kz * 128 + k];
    }
    __syncthreads();

    float acc[32];
    #pragma unroll
    for (int r = 0; r < 32; ++r) acc[r] = 0.f;

    const float* wrow = W + (size_t)c * K + kz * 128;
    for (int k4 = 0; k4 < 32; ++k4) {
        const float4 w = reinterpret_cast<const float4*>(wrow)[k4];
        #pragma unroll
        for (int r = 0; r < 32; ++r) {
            const float4 a = *reinterpret_cast<const float4*>(&As[r][k4 * 4]);
            acc[r] = fmaf(w.x, a.x, fmaf(w.y, a.y, fmaf(w.z, a.z, fmaf(w.w, a.w, acc[r]))));
        }
    }

    float* pp = P + ((size_t)kz * N + c) * 32;
    #pragma unroll
    for (int r = 0; r < 32; ++r) pp[r] = acc[r];
}

__global__ __launch_bounds__(256) void skreduce_kernel(
    const float* __restrict__ P, int KS, const float* __restrict__ bias,
    float* __restrict__ out, int N, int act)
{
    const int idx = blockIdx.x * 256 + threadIdx.x;
    const int r = idx & 31, c = idx >> 5;
    float s = 0.f;
    for (int kz = 0; kz < KS; ++kz)
        s += P[(size_t)kz * N * 32 + idx];
    s += bias[c];
    if (act == 2) s = s / (1.f + __expf(-s));
    out[(size_t)r * N + c] = s;
}

// ---------------------------------------------------------------------------
// MFMA causal flash attention, 4 q-tiles per block, fixed-base softmax.
// Block pr handles q-tiles {7-pr, pr, 5-pr, 2+pr} (pr=0: {7,0,5,2},
// pr=1: {6,1,4,3}; both 18 tile-steps). Grid (2, NHH, BB). Sout bf16.
// ---------------------------------------------------------------------------
__global__ __launch_bounds__(256) void mattn_kernel(
    const unsigned short* __restrict__ Q, const unsigned short* __restrict__ K,
    const unsigned short* __restrict__ VT, const unsigned short* __restrict__ Qin,
    unsigned short* __restrict__ Sout)
{
    __shared__ alignas(16) unsigned short kT[2][4096];
    __shared__ alignas(16) unsigned short vT[2][4096];
    __shared__ unsigned short pl[4][1024];

    const int pr = blockIdx.x;          // 0..1
    const int h  = blockIdx.y;
    const int b  = blockIdx.z;
    const int tid = threadIdx.x, lane = tid & 63, wid = tid >> 6;
    const int fr = lane & 15, fq = lane >> 4;
    const int hc = h * HDD;

    const int qts[4] = {7 - pr, pr, 5 - pr, 2 + pr};
    const int maxQt = 7 - pr;

    const int c0i = tid, c1i = 256 + tid;
    const int r0s = c0i >> 3, j0s = c0i & 7, d0s = ((j0s ^ (r0s & 7)) << 3);
    const int r1s = c1i >> 3, j1s = c1i & 7, d1s = ((j1s ^ (r1s & 7)) << 3);
    const unsigned short* kS0 = K + (size_t)b * LL * CHN + (size_t)r0s * CHN + hc + d0s;
    const unsigned short* kS1 = K + (size_t)b * LL * CHN + (size_t)r1s * CHN + hc + d1s;
    const unsigned short* vS0 = VT + ((size_t)(b * NHH + h) * 64 + r0s) * 512 + d0s;
    const unsigned short* vS1 = VT + ((size_t)(b * NHH + h) * 64 + r1s) * 512 + d1s;

    #define AT_STAGE(buf, ch)                                              \
        do {                                                               \
            const int o = (ch) * 64;                                       \
            gl16(kS0 + (size_t)o * CHN, &kT[buf][wid * 512]);              \
            gl16(kS1 + (size_t)o * CHN, &kT[buf][2048 + wid * 512]);       \
            gl16(vS0 + o, &vT[buf][wid * 512]);                            \
            gl16(vS1 + o, &vT[buf][2048 + wid * 512]);                     \
        } while (0)

    // Q fragments for 4 tiles: row = fr, k = kk*32 + fq*8
    short8 qf[4][2];
    #pragma unroll
    for (int s = 0; s < 4; ++s) {
        const size_t qrow = (size_t)b * LL + qts[s] * 64 + wid * 16 + fr;
        qf[s][0] = *reinterpret_cast<const short8*>(Q + qrow * CHN + hc + fq * 8);
        qf[s][1] = *reinterpret_cast<const short8*>(Q + qrow * CHN + hc + 32 + fq * 8);
    }

    f32x4 oacc[4][4];
    float lrow[4][4];
    #pragma unroll
    for (int s = 0; s < 4; ++s) {
        #pragma unroll
        for (int n = 0; n < 4; ++n) oacc[s][n] = (f32x4){0.f, 0.f, 0.f, 0.f};
        #pragma unroll
        for (int r = 0; r < 4; ++r) lrow[s][r] = 0.f;
    }

    auto tile_step = [&](int cur, int qt, int ch, const short8* qfs,
                         f32x4* oa, float* lr) {
        f32x4 sacc[4];
        #pragma unroll
        for (int n = 0; n < 4; ++n) sacc[n] = (f32x4){0.f, 0.f, 0.f, 0.f};
        __builtin_amdgcn_s_setprio(1);
        #pragma unroll
        for (int kk = 0; kk < 2; ++kk) {
            #pragma unroll
            for (int n = 0; n < 4; ++n) {
                const short8 kf = *reinterpret_cast<const short8*>(
                    &kT[cur][SWZ(n * 16 + fr, kk * 32 + fq * 8)]);
                sacc[n] = __builtin_amdgcn_mfma_f32_16x16x32_bf16(qfs[kk], kf, sacc[n], 0, 0, 0);
            }
        }
        __builtin_amdgcn_s_setprio(0);

        const bool diag = (ch == qt);
        #pragma unroll
        for (int r = 0; r < 4; ++r) {
            float sv[4];
            #pragma unroll
            for (int n = 0; n < 4; ++n) {
                float v = sacc[n][r];
                if (diag && (n * 16 + fr > wid * 16 + fq * 4 + r)) v = -1e30f;
                sv[n] = __expf(v);
            }
            float ps = (sv[0] + sv[1]) + (sv[2] + sv[3]);
            ps += __shfl_xor(ps, 1);
            ps += __shfl_xor(ps, 2);
            ps += __shfl_xor(ps, 4);
            ps += __shfl_xor(ps, 8);
            lr[r] += ps;
            #pragma unroll
            for (int n = 0; n < 4; ++n)
                pl[wid][SWZ(fq * 4 + r, n * 16 + fr)] = f2b(sv[n]);
        }

        __builtin_amdgcn_s_setprio(1);
        #pragma unroll
        for (int kk = 0; kk < 2; ++kk) {
            const short8 pa = *reinterpret_cast<const short8*>(
                &pl[wid][SWZ(fr, kk * 32 + fq * 8)]);
            #pragma unroll
            for (int n = 0; n < 4; ++n) {
                const short8 vf = *reinterpret_cast<const short8*>(
                    &vT[cur][SWZ(n * 16 + fr, kk * 32 + fq * 8)]);
                oa[n] = __builtin_amdgcn_mfma_f32_16x16x32_bf16(pa, vf, oa[n], 0, 0, 0);
            }
        }
        __builtin_amdgcn_s_setprio(0);
    };

    AT_STAGE(0, 0);
    __syncthreads();

    for (int ch = 0; ch <= maxQt; ++ch) {
        const int cur = ch & 1;
        if (ch < maxQt) AT_STAGE(cur ^ 1, ch + 1);

        #pragma unroll
        for (int s = 0; s < 4; ++s)
            if (ch <= qts[s])
                tile_step(cur, qts[s], ch, qf[s], oacc[s], lrow[s]);

        __syncthreads();  // all reads of kT/vT[cur] done; next stage may land
    }
    #undef AT_STAGE

    #pragma unroll
    for (int s = 0; s < 4; ++s) {
        const size_t orow0 = (size_t)b * LL + qts[s] * 64 + wid * 16 + fq * 4;
        #pragma unroll
        for (int r = 0; r < 4; ++r) {
            const float inv = 1.f / lrow[s][r];
            const size_t rowidx = (orow0 + r) * CHN + hc;
            #pragma unroll
            for (int n = 0; n < 4; ++n) {
                const int d = n * 16 + fr;
                Sout[rowidx + d] = f2b(oacc[s][n][r] * inv + b2f(Qin[rowidx + d]));
            }
        }
    }
}

// ---------------------------------------------------------------------------
__global__ __launch_bounds__(256) void temb_embed_kernel(
    const int* __restrict__ t, float* __restrict__ T0)
{
    const int idx = blockIdx.x * 256 + threadIdx.x;
    const int b = idx >> 9, j = idx & 511;
    const float tv = (float)t[b];
    const int jj = (j < 256) ? j : j - 256;
    const float freq = __expf((float)jj * (-9.210340371976184f / 255.f));
    const float ang = tv * freq;
    T0[idx] = (j < 256) ? sinf(ang) : cosf(ang);
}

__global__ __launch_bounds__(256) void add_temb_kernel(
    const float* __restrict__ xin, const float* __restrict__ temb,
    unsigned short* __restrict__ out)
{
    const size_t i4 = (size_t)blockIdx.x * 256 + threadIdx.x;
    const size_t elem = i4 * 4;
    const int b = (int)(elem >> 18);
    const int c = (int)(elem & (CHN - 1));
    const float4 a = reinterpret_cast<const float4*>(xin)[i4];
    const float4 tv = *reinterpret_cast<const float4*>(temb + (size_t)b * CHN + c);
    ushort4 o;
    o.x = f2b(a.x + tv.x); o.y = f2b(a.y + tv.y);
    o.z = f2b(a.z + tv.z); o.w = f2b(a.w + tv.w);
    reinterpret_cast<ushort4*>(out)[i4] = o;
}

// ---------------------------------------------------------------------------
extern "C" void kernel_launch(void* const* d_in, const int* in_sizes, int n_in,
                              void* d_out, int out_size, void* d_ws, size_t ws_size,
                              hipStream_t stream)
{
    (void)in_sizes; (void)n_in; (void)out_size; (void)ws_size;
    const float* log_seqs = (const float*)d_in[0];
    const float* seqs_nxt = (const float*)d_in[1];
    const int*   tt       = (const int*)d_in[2];
    const float* qw  = (const float*)d_in[3];
    const float* qb  = (const float*)d_in[4];
    const float* kw  = (const float*)d_in[5];
    const float* kb  = (const float*)d_in[6];
    const float* vw  = (const float*)d_in[7];
    const float* vb  = (const float*)d_in[8];
    const float* ln1g = (const float*)d_in[9];
    const float* ln1b = (const float*)d_in[10];
    const float* ln2g = (const float*)d_in[11];
    const float* ln2b = (const float*)d_in[12];
    const float* c1w = (const float*)d_in[13];
    const float* c1b = (const float*)d_in[14];
    const float* c2w = (const float*)d_in[15];
    const float* c2b = (const float*)d_in[16];
    const float* posK = (const float*)d_in[17];
    const float* posV = (const float*)d_in[18];
    const float* lng = (const float*)d_in[19];
    const float* lnb = (const float*)d_in[20];
    const float* tw0 = (const float*)d_in[21];
    const float* tb0 = (const float*)d_in[22];
    const float* tw1 = (const float*)d_in[23];
    const float* tb1 = (const float*)d_in[24];
    const float* tw2 = (const float*)d_in[25];
    const float* tb2 = (const float*)d_in[26];
    const float* decw = (const float*)d_in[27];
    const float* decb = (const float*)d_in[28];

    const size_t SZ = (size_t)BB * LL * CHN;  // 8388608
    const int M = BB * LL;                    // 16384
    float* out = (float*)d_out;
    float* log_feats = out;
    float* dec = out + SZ;
    unsigned short* QBb = (unsigned short*)dec;        // Q bf16 until decoder
    unsigned short* VTb = (unsigned short*)log_feats;  // V^T bf16 until final LN

    float* ws = (float*)d_ws;
    unsigned short* SB = (unsigned short*)ws;                 // residual stream bf16
    float* P = ws + SZ / 2;                                   // split-K partials
    unsigned short* KBb = (unsigned short*)(ws + SZ);
    unsigned short* R0  = (unsigned short*)(ws + SZ + SZ / 2);
    unsigned short* R1  = (unsigned short*)(ws + 2 * SZ);
    unsigned short* WBu = (unsigned short*)(ws + 2 * SZ + SZ / 2);  // 3145728 bf16
    float* T0 = ws + 2 * SZ + SZ / 2 + 1572864;
    float* T1 = T0 + 32 * CHN;
    float* T2 = T1 + 32 * 2048;
    float* T3 = T2 + 32 * 2048;

    const size_t WQ = 0, WKV = 524288, WC1 = 1572864,
                 WC2 = 2097152, WDEC = 2621440;

    auto mg = [&](const unsigned short* A, const unsigned short* W, int ldw,
                  const float* bias, const float* pos, const unsigned short* resb,
                  float* outf, unsigned short* outb, unsigned short* outbt, int act) {
        mgemm_kernel<<<256, 512, 0, stream>>>(A, W, ldw, bias, pos, resb,
                                              outf, outb, outbt, act);
    };
    auto skg = [&](const float* A, int K, const float* W, int N,
                   const float* bias, float* o, int act) {
        skgemm_kernel<<<dim3(N / 256, K / 128), 256, 0, stream>>>(A, K, W, N, P);
        skreduce_kernel<<<(N * 32) / 256, 256, 0, stream>>>(P, K / 128, bias, o, N, act);
    };

    // weight + input conversions in one launch
    cvt7_kernel<<<dim3(512, 7), 256, 0, stream>>>(qw, kw, vw, c1w, c2w, decw, WBu,
                                                  log_seqs, R1);

    // per layer: R1 -> ln1 -> R0 -> qkv2(Q from R0, KV from R1) -> mattn -> SB
    //            -> ln2(SB in-place) -> c1 -> R0 -> c2(+SB res) -> R1
    for (int i = 0; i < 2; ++i) {
        const size_t wo = (size_t)i * 262144;
        const size_t bo = (size_t)i * CHN;

        ln_kernel<<<M, 256, 0, stream>>>(R1, ln1g + bo, ln1b + bo, nullptr, R0);
        qkv2_kernel<<<768, 512, 0, stream>>>(
            R0, R1, WBu + WQ + wo, WBu + WKV + (size_t)i * 524288,
            qb + bo, kb + bo, vb + bo, posK, posV, QBb, KBb, VTb);
        mattn_kernel<<<dim3(2, NHH, BB), 256, 0, stream>>>(QBb, KBb, VTb, R0, SB);
        ln_kernel<<<M, 256, 0, stream>>>(SB, ln2g + bo, ln2b + bo, nullptr, SB);
        mg(SB, WBu + WC1 + wo, 512, c1b + bo, nullptr, nullptr, nullptr, R0, nullptr, 1);
        mg(R0, WBu + WC2 + wo, 512, c2b + bo, nullptr, SB, nullptr, R1, nullptr, 0);
    }

    ln_kernel<<<M, 256, 0, stream>>>(R1, lng, lnb, log_feats, R0);

    temb_embed_kernel<<<(BB * CHN) / 256, 256, 0, stream>>>(tt, T0);
    skg(T0, 512, tw0, 2048, tb0, T1, 2);
    skg(T1, 2048, tw1, 2048, tb1, T2, 2);
    skg(T2, 2048, tw2, 512, tb2, T3, 0);
    add_temb_kernel<<<(M * CHN / 4) / 256, 256, 0, stream>>>(seqs_nxt, T3, R1);

    dec_kernel<<<256, 512, 0, stream>>>(R0, R1, WBu + WDEC, decb, dec);
}

// Round 17
// 596.418 us; speedup vs baseline: 1.0985x; 1.0985x over previous
//
#include <hip/hip_runtime.h>
#include <math.h>

#define BB 32
#define LL 512
#define CHN 512
#define NHH 8
#define HDD 64

typedef __attribute__((ext_vector_type(8))) short short8;
typedef __attribute__((ext_vector_type(4))) float f32x4;

__device__ __forceinline__ float b2f(unsigned short s) {
    union { unsigned int u; float f; } c; c.u = ((unsigned int)s) << 16; return c.f;
}
__device__ __forceinline__ unsigned short f2b(float f) {
    union { float f; unsigned int u; } c; c.f = f;
    return (unsigned short)((c.u + 0x7fffu + ((c.u >> 16) & 1u)) >> 16);
}

// swizzled ushort index for a [rows][64] bf16 LDS tile (breaks 128B-stride conflicts)
#define SWZ(row, col) ((((row) * 64 + (col))) ^ (((row) & 7) << 3))

__device__ __forceinline__ void gl16(const unsigned short* g, unsigned short* l) {
    __builtin_amdgcn_global_load_lds(
        (const __attribute__((address_space(1))) unsigned int*)g,
        (__attribute__((address_space(3))) unsigned int*)l, 16, 0, 0);
}

// ---------------------------------------------------------------------------
// Weight slab (bf16 ushorts):
//   [0,524288)          qw  L0,L1
//   [524288,1572864)    KV: per layer contiguous [kw_i(512x512); vw_i(512x512)]
//   [1572864,2097152)   c1w L0,L1
//   [2097152,2621440)   c2w L0,L1
//   [2621440,3145728)   decw
// cvt7 also converts log_seqs -> R1.
// ---------------------------------------------------------------------------
__global__ __launch_bounds__(256) void cvt7_kernel(
    const float* __restrict__ p0, const float* __restrict__ p1,
    const float* __restrict__ p2, const float* __restrict__ p3,
    const float* __restrict__ p4, const float* __restrict__ p5,
    unsigned short* __restrict__ y,
    const float* __restrict__ seqs, unsigned short* __restrict__ R1)
{
    const int j = blockIdx.y;
    const int i = blockIdx.x * 256 + threadIdx.x;   // 0..131071 (float4 units)
    if (j < 6) {
        const float* x = j == 0 ? p0 : j == 1 ? p1 : j == 2 ? p2
                       : j == 3 ? p3 : j == 4 ? p4 : p5;
        const float4 v = reinterpret_cast<const float4*>(x)[i];
        ushort4 o;
        o.x = f2b(v.x); o.y = f2b(v.y); o.z = f2b(v.z); o.w = f2b(v.w);
        size_t dst4;
        if (j == 1)      dst4 = 131072 + i + (i >= 65536 ? 65536 : 0);          // kw
        else if (j == 2) dst4 = 131072 + 65536 + i + (i >= 65536 ? 65536 : 0);  // vw
        else             dst4 = (size_t)j * 131072 + i;  // qw(0), c1(3), c2(4), dec(5)
        reinterpret_cast<ushort4*>(y)[dst4] = o;
    } else {
        #pragma unroll
        for (int t = 0; t < 16; ++t) {
            const int ii = t * 131072 + i;
            const float4 v = reinterpret_cast<const float4*>(seqs)[ii];
            ushort4 o;
            o.x = f2b(v.x); o.y = f2b(v.y); o.z = f2b(v.z); o.w = f2b(v.w);
            reinterpret_cast<ushort4*>(R1)[ii] = o;
        }
    }
}

// ---------------------------------------------------------------------------
// Row LayerNorm over CH=512 (eps=1e-8), bf16 input, f32 stats.
// ---------------------------------------------------------------------------
__global__ __launch_bounds__(256) void ln_kernel(
    const unsigned short* __restrict__ x, const float* __restrict__ g,
    const float* __restrict__ b, float* __restrict__ yf,
    unsigned short* __restrict__ yb)
{
    const int row = blockIdx.x;
    const int tid = threadIdx.x;
    const size_t base = (size_t)row * CHN;
    const ushort2 v2 = *reinterpret_cast<const ushort2*>(x + base + tid * 2);
    const float vx = b2f(v2.x), vy = b2f(v2.y);
    float s  = vx + vy;
    float ss = vx * vx + vy * vy;
    #pragma unroll
    for (int m = 1; m < 64; m <<= 1) {
        s  += __shfl_xor(s, m);
        ss += __shfl_xor(ss, m);
    }
    __shared__ float red[8];
    const int wave = tid >> 6;
    if ((tid & 63) == 0) { red[wave] = s; red[4 + wave] = ss; }
    __syncthreads();
    s  = red[0] + red[1] + red[2] + red[3];
    ss = red[4] + red[5] + red[6] + red[7];
    const float mean = s * (1.0f / CHN);
    const float var  = ss * (1.0f / CHN) - mean * mean;
    const float inv  = rsqrtf(var + 1e-8f);
    const int c = tid * 2;
    float ox = (vx - mean) * inv * g[c]     + b[c];
    float oy = (vy - mean) * inv * g[c + 1] + b[c + 1];
    if (yf) *reinterpret_cast<float2*>(yf + base + c) = make_float2(ox, oy);
    if (yb) {
        ushort2 ob; ob.x = f2b(ox); ob.y = f2b(oy);
        *reinterpret_cast<ushort2*>(yb + base + c) = ob;
    }
}

// ---------------------------------------------------------------------------
// bf16 MFMA GEMM body (depth-3, measured-best): 256x128 tile, BK=32,
// 8 waves (4x2). NBX = N/128 tiles. act: 0=none 1=relu 3=scale-by-0.125.
// ---------------------------------------------------------------------------
template <int NT, int NBX>
__device__ __forceinline__ void gemm_body(
    const unsigned short* __restrict__ A,
    const unsigned short* __restrict__ A2,
    const unsigned short* __restrict__ W, int ldw,
    const float* __restrict__ bias,
    const float* __restrict__ pos,
    const unsigned short* __restrict__ resb,
    float* __restrict__ outf,
    unsigned short* __restrict__ outb,
    unsigned short* __restrict__ outbt,
    int act, int bid,
    unsigned short* lA, unsigned short* lB)
{
    const int tid  = threadIdx.x;
    const int lane = tid & 63;
    const int wid  = tid >> 6;          // 0..7

    const int swz = (bid & 7) * (NBX * 8) + (bid >> 3);
    const int by = swz / NBX, bx = swz % NBX;
    const int bm = by * 256, bn = bx * 128;

    const int ia0 = wid * 2, ia1 = wid * 2 + 1;
    const int hiA0 = ia0 >> 2, rgA0 = ia0 & 3;
    const int hiA1 = ia1 >> 2, rgA1 = ia1 & 3;
    const int hiB = wid >> 1, rgB = wid & 1;

    const unsigned short* Ax = A2 ? A2 : A;
    const unsigned short* aS0  = A  + (size_t)(bm + rgA0 * 64 + lane) * 512 + hiA0 * 8;
    const unsigned short* aS1  = A  + (size_t)(bm + rgA1 * 64 + lane) * 512 + hiA1 * 8;
    const unsigned short* a2S0 = Ax + (size_t)(bm + rgA0 * 64 + lane) * 512 + hiA0 * 8;
    const unsigned short* a2S1 = Ax + (size_t)(bm + rgA1 * 64 + lane) * 512 + hiA1 * 8;
    const unsigned short* wS   = W + (size_t)(bn + rgB * 64 + lane) * ldw + hiB * 8;
    const int dA0 = (hiA0 * 256 + rgA0 * 64) * 8;
    const int dA1 = (hiA1 * 256 + rgA1 * 64) * 8;
    const int dB  = (hiB * 128 + rgB * 64) * 8;

    const int wr = wid >> 1, wc = wid & 1;
    const int fr = lane & 15;
    const int fq = lane >> 4;

    f32x4 acc[4][4];
    #pragma unroll
    for (int m = 0; m < 4; ++m)
        #pragma unroll
        for (int n = 0; n < 4; ++n)
            acc[m][n] = (f32x4){0.f, 0.f, 0.f, 0.f};

    #define MG_STAGE(buf, t)                                            \
        do {                                                            \
            const int k0 = ((t) & 15) * 32;                             \
            const unsigned short* s0 = ((t) < 16) ? aS0 : a2S0;         \
            const unsigned short* s1 = ((t) < 16) ? aS1 : a2S1;         \
            gl16(s0 + k0, &lA[(buf) * 8192 + dA0]);                     \
            gl16(s1 + k0, &lA[(buf) * 8192 + dA1]);                     \
            gl16(wS + (t) * 32, &lB[(buf) * 4096 + dB]);                \
        } while (0)

    MG_STAGE(0, 0);
    MG_STAGE(1, 1);

    #pragma unroll
    for (int t = 0; t < NT; ++t) {
        const int cur = t % 3;
        if (t + 2 < NT) {
            MG_STAGE((t + 2) % 3, t + 2);
            asm volatile("s_waitcnt vmcnt(6)" ::: "memory");
        } else if (t + 1 < NT) {
            asm volatile("s_waitcnt vmcnt(3)" ::: "memory");
        } else {
            asm volatile("s_waitcnt vmcnt(0)" ::: "memory");
        }
        __builtin_amdgcn_s_barrier();

        const unsigned short* pa = &lA[cur * 8192 + (fq * 256 + wr * 64 + fr) * 8];
        const unsigned short* pb = &lB[cur * 4096 + (fq * 128 + wc * 64 + fr) * 8];
        short8 aF[4], bF[4];
        #pragma unroll
        for (int m = 0; m < 4; ++m)
            aF[m] = *reinterpret_cast<const short8*>(pa + m * 128);
        #pragma unroll
        for (int n = 0; n < 4; ++n)
            bF[n] = *reinterpret_cast<const short8*>(pb + n * 128);
        asm volatile("s_waitcnt lgkmcnt(0)" ::: "memory");
        __builtin_amdgcn_s_barrier();

        __builtin_amdgcn_s_setprio(1);
        #pragma unroll
        for (int m = 0; m < 4; ++m)
            #pragma unroll
            for (int n = 0; n < 4; ++n)
                acc[m][n] = __builtin_amdgcn_mfma_f32_16x16x32_bf16(
                    aF[m], bF[n], acc[m][n], 0, 0, 0);
        __builtin_amdgcn_s_setprio(0);
    }
    #undef MG_STAGE

    const int row0 = bm + wr * 64, col0 = bn + wc * 64;
    #pragma unroll
    for (int m = 0; m < 4; ++m) {
        #pragma unroll
        for (int n = 0; n < 4; ++n) {
            const int col = col0 + n * 16 + fr;
            const float bia = bias ? bias[col] : 0.f;
            ushort4 o4;
            #pragma unroll
            for (int r = 0; r < 4; ++r) {
                const int row = row0 + m * 16 + fq * 4 + r;
                float v = acc[m][n][r] + bia;
                if (pos) v += pos[(size_t)(row & (LL - 1)) * CHN + col];
                if (act == 1) v = fmaxf(v, 0.f);
                else if (act == 3) v *= 0.125f;
                const size_t idx = (size_t)row * CHN + col;
                if (resb) v += b2f(resb[idx]);
                if (outf) outf[idx] = v;
                if (outb) outb[idx] = f2b(v);
                ((unsigned short*)&o4)[r] = f2b(v);
            }
            if (outbt) {
                const int rw = row0 + m * 16 + fq * 4;
                *reinterpret_cast<ushort4*>(
                    &outbt[((size_t)(rw >> 9) * 512 + col) * 512 + (rw & 511)]) = o4;
            }
        }
    }
}

// ---------------------------------------------------------------------------
// KV body: N=1024 GEMM over W_kv = [kw;vw], depth-3. Block-uniform epilogue
// split: bn<512 -> K (posK, KBb); bn>=512 -> V (posV, VTb transposed).
// ---------------------------------------------------------------------------
__device__ __forceinline__ void kv_body(
    const unsigned short* __restrict__ A,
    const unsigned short* __restrict__ Wkv,
    const float* __restrict__ kb, const float* __restrict__ vb,
    const float* __restrict__ posK, const float* __restrict__ posV,
    unsigned short* __restrict__ KBb, unsigned short* __restrict__ VTb,
    int bid, unsigned short* lA, unsigned short* lB)
{
    const int tid  = threadIdx.x;
    const int lane = tid & 63;
    const int wid  = tid >> 6;

    const int swz = (bid & 7) * 64 + (bid >> 3);   // 512 blocks
    const int by = swz >> 3, bx = swz & 7;
    const int bm = by * 256, bn = bx * 128;

    const int ia0 = wid * 2, ia1 = wid * 2 + 1;
    const int hiA0 = ia0 >> 2, rgA0 = ia0 & 3;
    const int hiA1 = ia1 >> 2, rgA1 = ia1 & 3;
    const int hiB = wid >> 1, rgB = wid & 1;

    const unsigned short* aS0 = A + (size_t)(bm + rgA0 * 64 + lane) * 512 + hiA0 * 8;
    const unsigned short* aS1 = A + (size_t)(bm + rgA1 * 64 + lane) * 512 + hiA1 * 8;
    const unsigned short* wS  = Wkv + (size_t)(bn + rgB * 64 + lane) * 512 + hiB * 8;
    const int dA0 = (hiA0 * 256 + rgA0 * 64) * 8;
    const int dA1 = (hiA1 * 256 + rgA1 * 64) * 8;
    const int dB  = (hiB * 128 + rgB * 64) * 8;

    const int wr = wid >> 1, wc = wid & 1;
    const int fr = lane & 15;
    const int fq = lane >> 4;

    f32x4 acc[4][4];
    #pragma unroll
    for (int m = 0; m < 4; ++m)
        #pragma unroll
        for (int n = 0; n < 4; ++n)
            acc[m][n] = (f32x4){0.f, 0.f, 0.f, 0.f};

    #define KV_STAGE(buf, t)                                            \
        do {                                                            \
            const int k0 = (t) * 32;                                    \
            gl16(aS0 + k0, &lA[(buf) * 8192 + dA0]);                    \
            gl16(aS1 + k0, &lA[(buf) * 8192 + dA1]);                    \
            gl16(wS + k0, &lB[(buf) * 4096 + dB]);                      \
        } while (0)

    KV_STAGE(0, 0);
    KV_STAGE(1, 1);

    #pragma unroll
    for (int t = 0; t < 16; ++t) {
        const int cur = t % 3;
        if (t + 2 < 16) {
            KV_STAGE((t + 2) % 3, t + 2);
            asm volatile("s_waitcnt vmcnt(6)" ::: "memory");
        } else if (t + 1 < 16) {
            asm volatile("s_waitcnt vmcnt(3)" ::: "memory");
        } else {
            asm volatile("s_waitcnt vmcnt(0)" ::: "memory");
        }
        __builtin_amdgcn_s_barrier();

        const unsigned short* pa = &lA[cur * 8192 + (fq * 256 + wr * 64 + fr) * 8];
        const unsigned short* pb = &lB[cur * 4096 + (fq * 128 + wc * 64 + fr) * 8];
        short8 aF[4], bF[4];
        #pragma unroll
        for (int m = 0; m < 4; ++m)
            aF[m] = *reinterpret_cast<const short8*>(pa + m * 128);
        #pragma unroll
        for (int n = 0; n < 4; ++n)
            bF[n] = *reinterpret_cast<const short8*>(pb + n * 128);
        asm volatile("s_waitcnt lgkmcnt(0)" ::: "memory");
        __builtin_amdgcn_s_barrier();

        __builtin_amdgcn_s_setprio(1);
        #pragma unroll
        for (int m = 0; m < 4; ++m)
            #pragma unroll
            for (int n = 0; n < 4; ++n)
                acc[m][n] = __builtin_amdgcn_mfma_f32_16x16x32_bf16(
                    aF[m], bF[n], acc[m][n], 0, 0, 0);
        __builtin_amdgcn_s_setprio(0);
    }
    #undef KV_STAGE

    const int row0 = bm + wr * 64;
    if (bn < 512) {
        const int col0 = bn + wc * 64;
        #pragma unroll
        for (int m = 0; m < 4; ++m) {
            #pragma unroll
            for (int n = 0; n < 4; ++n) {
                const int col = col0 + n * 16 + fr;
                const float bia = kb[col];
                #pragma unroll
                for (int r = 0; r < 4; ++r) {
                    const int row = row0 + m * 16 + fq * 4 + r;
                    float v = acc[m][n][r] + bia
                            + posK[(size_t)(row & (LL - 1)) * CHN + col];
                    KBb[(size_t)row * CHN + col] = f2b(v);
                }
            }
        }
    } else {
        const int vcol0 = (bn - 512) + wc * 64;
        #pragma unroll
        for (int m = 0; m < 4; ++m) {
            #pragma unroll
            for (int n = 0; n < 4; ++n) {
                const int vcol = vcol0 + n * 16 + fr;
                const float bia = vb[vcol];
                ushort4 o4;
                #pragma unroll
                for (int r = 0; r < 4; ++r) {
                    const int row = row0 + m * 16 + fq * 4 + r;
                    float v = acc[m][n][r] + bia
                            + posV[(size_t)(row & (LL - 1)) * CHN + vcol];
                    ((unsigned short*)&o4)[r] = f2b(v);
                }
                const int rw = row0 + m * 16 + fq * 4;
                *reinterpret_cast<ushort4*>(
                    &VTb[((size_t)(rw >> 9) * 512 + vcol) * 512 + (rw & 511)]) = o4;
            }
        }
    }
}

__global__ __launch_bounds__(512) void mgemm_kernel(
    const unsigned short* __restrict__ A,
    const unsigned short* __restrict__ W, int ldw,
    const float* __restrict__ bias,
    const float* __restrict__ pos,
    const unsigned short* __restrict__ resb,
    float* __restrict__ outf,
    unsigned short* __restrict__ outb,
    unsigned short* __restrict__ outbt,
    int act)
{
    __shared__ alignas(16) unsigned short lA[3 * 8192];
    __shared__ alignas(16) unsigned short lB[3 * 4096];
    gemm_body<16, 4>(A, nullptr, W, ldw, bias, pos, resb, outf, outb, outbt, act,
                     blockIdx.x, lA, lB);
}

// Fused Q + KV: blocks 0-255 = Q GEMM (A=qinb), 256-767 = KV GEMM (A=curb).
__global__ __launch_bounds__(512) void qkv2_kernel(
    const unsigned short* __restrict__ qinb, const unsigned short* __restrict__ curb,
    const unsigned short* __restrict__ Wq, const unsigned short* __restrict__ Wkv,
    const float* __restrict__ qb, const float* __restrict__ kb,
    const float* __restrict__ vb,
    const float* __restrict__ posK, const float* __restrict__ posV,
    unsigned short* __restrict__ QBb, unsigned short* __restrict__ KBb,
    unsigned short* __restrict__ VTb)
{
    __shared__ alignas(16) unsigned short lA[3 * 8192];
    __shared__ alignas(16) unsigned short lB[3 * 4096];
    if (blockIdx.x < 256) {
        gemm_body<16, 4>(qinb, nullptr, Wq, 512, qb, nullptr, nullptr,
                         nullptr, QBb, nullptr, 3, blockIdx.x, lA, lB);
    } else {
        kv_body(curb, Wkv, kb, vb, posK, posV, KBb, VTb, blockIdx.x - 256, lA, lB);
    }
}

// Decoder fused: dec = [log_feats | x_t] @ decw^T + decb  (K=1024, two A sources)
__global__ __launch_bounds__(512) void dec_kernel(
    const unsigned short* __restrict__ R0b, const unsigned short* __restrict__ R1b,
    const unsigned short* __restrict__ Wd, const float* __restrict__ decb,
    float* __restrict__ dec)
{
    __shared__ alignas(16) unsigned short lA[3 * 8192];
    __shared__ alignas(16) unsigned short lB[3 * 4096];
    gemm_body<32, 4>(R0b, R1b, Wd, 1024, decb, nullptr, nullptr, dec, nullptr,
                     nullptr, 0, blockIdx.x, lA, lB);
}

// ---------------------------------------------------------------------------
// Split-K small-M GEMM for the temb path.
// ---------------------------------------------------------------------------
__global__ __launch_bounds__(256) void skgemm_kernel(
    const float* __restrict__ A, int K,
    const float* __restrict__ W, int N,
    float* __restrict__ P)
{
    __shared__ float As[32][128];
    const int tid = threadIdx.x;
    const int kz  = blockIdx.y;
    const int c   = blockIdx.x * 256 + tid;

    #pragma unroll
    for (int i = 0; i < 16; ++i) {
        const int idx = i * 256 + tid;
        const int r = idx >> 7, k = idx & 127;
        As[r][k] = A[(size_t)r * K + kz * 128 + k];
    }
    __syncthreads();

    float acc[32];
    #pragma unroll
    for (int r = 0; r < 32; ++r) acc[r] = 0.f;

    const float* wrow = W + (size_t)c * K + kz * 128;
    for (int k4 = 0; k4 < 32; ++k4) {
        const float4 w = reinterpret_cast<const float4*>(wrow)[k4];
        #pragma unroll
        for (int r = 0; r < 32; ++r) {
            const float4 a = *reinterpret_cast<const float4*>(&As[r][k4 * 4]);
            acc[r] = fmaf(w.x, a.x, fmaf(w.y, a.y, fmaf(w.z, a.z, fmaf(w.w, a.w, acc[r]))));
        }
    }

    float* pp = P + ((size_t)kz * N + c) * 32;
    #pragma unroll
    for (int r = 0; r < 32; ++r) pp[r] = acc[r];
}

__global__ __launch_bounds__(256) void skreduce_kernel(
    const float* __restrict__ P, int KS, const float* __restrict__ bias,
    float* __restrict__ out, int N, int act)
{
    const int idx = blockIdx.x * 256 + threadIdx.x;
    const int r = idx & 31, c = idx >> 5;
    float s = 0.f;
    for (int kz = 0; kz < KS; ++kz)
        s += P[(size_t)kz * N * 32 + idx];
    s += bias[c];
    if (act == 2) s = s / (1.f + __expf(-s));
    out[(size_t)r * N + c] = s;
}

// ---------------------------------------------------------------------------
// MFMA causal flash attention, paired q-tiles (r14 measured-best),
// fixed-base softmax. Block pr handles (pr, 7-pr): 9 chunks each. Sout bf16.
// ---------------------------------------------------------------------------
__global__ __launch_bounds__(256) void mattn_kernel(
    const unsigned short* __restrict__ Q, const unsigned short* __restrict__ K,
    const unsigned short* __restrict__ VT, const unsigned short* __restrict__ Qin,
    unsigned short* __restrict__ Sout)
{
    __shared__ alignas(16) unsigned short kT[2][4096];
    __shared__ alignas(16) unsigned short vT[2][4096];
    __shared__ unsigned short pl[4][1024];

    const int pr = blockIdx.x;          // 0..3
    const int qtA = pr, qtB = 7 - pr;
    const int h  = blockIdx.y;
    const int b  = blockIdx.z;
    const int tid = threadIdx.x, lane = tid & 63, wid = tid >> 6;
    const int fr = lane & 15, fq = lane >> 4;
    const int hc = h * HDD;

    const int c0i = tid, c1i = 256 + tid;
    const int r0s = c0i >> 3, j0s = c0i & 7, d0s = ((j0s ^ (r0s & 7)) << 3);
    const int r1s = c1i >> 3, j1s = c1i & 7, d1s = ((j1s ^ (r1s & 7)) << 3);
    const unsigned short* kS0 = K + (size_t)b * LL * CHN + (size_t)r0s * CHN + hc + d0s;
    const unsigned short* kS1 = K + (size_t)b * LL * CHN + (size_t)r1s * CHN + hc + d1s;
    const unsigned short* vS0 = VT + ((size_t)(b * NHH + h) * 64 + r0s) * 512 + d0s;
    const unsigned short* vS1 = VT + ((size_t)(b * NHH + h) * 64 + r1s) * 512 + d1s;

    #define AT_STAGE(buf, ch)                                              \
        do {                                                               \
            const int o = (ch) * 64;                                       \
            gl16(kS0 + (size_t)o * CHN, &kT[buf][wid * 512]);              \
            gl16(kS1 + (size_t)o * CHN, &kT[buf][2048 + wid * 512]);       \
            gl16(vS0 + o, &vT[buf][wid * 512]);                            \
            gl16(vS1 + o, &vT[buf][2048 + wid * 512]);                     \
        } while (0)

    const size_t qrowA = (size_t)b * LL + qtA * 64 + wid * 16 + fr;
    const size_t qrowB = (size_t)b * LL + qtB * 64 + wid * 16 + fr;
    short8 qfA[2], qfB[2];
    qfA[0] = *reinterpret_cast<const short8*>(Q + qrowA * CHN + hc + fq * 8);
    qfA[1] = *reinterpret_cast<const short8*>(Q + qrowA * CHN + hc + 32 + fq * 8);
    qfB[0] = *reinterpret_cast<const short8*>(Q + qrowB * CHN + hc + fq * 8);
    qfB[1] = *reinterpret_cast<const short8*>(Q + qrowB * CHN + hc + 32 + fq * 8);

    f32x4 oaccA[4], oaccB[4];
    float lA_[4], lB_[4];
    #pragma unroll
    for (int n = 0; n < 4; ++n) {
        oaccA[n] = (f32x4){0.f, 0.f, 0.f, 0.f};
        oaccB[n] = (f32x4){0.f, 0.f, 0.f, 0.f};
    }
    #pragma unroll
    for (int r = 0; r < 4; ++r) { lA_[r] = 0.f; lB_[r] = 0.f; }

    auto tile_step = [&](int cur, int qt, int ch, const short8* qf,
                         f32x4* oacc, float* lrow) {
        f32x4 sacc[4];
        #pragma unroll
        for (int n = 0; n < 4; ++n) sacc[n] = (f32x4){0.f, 0.f, 0.f, 0.f};
        __builtin_amdgcn_s_setprio(1);
        #pragma unroll
        for (int kk = 0; kk < 2; ++kk) {
            #pragma unroll
            for (int n = 0; n < 4; ++n) {
                const short8 kf = *reinterpret_cast<const short8*>(
                    &kT[cur][SWZ(n * 16 + fr, kk * 32 + fq * 8)]);
                sacc[n] = __builtin_amdgcn_mfma_f32_16x16x32_bf16(qf[kk], kf, sacc[n], 0, 0, 0);
            }
        }
        __builtin_amdgcn_s_setprio(0);

        const bool diag = (ch == qt);
        #pragma unroll
        for (int r = 0; r < 4; ++r) {
            float sv[4];
            #pragma unroll
            for (int n = 0; n < 4; ++n) {
                float v = sacc[n][r];
                if (diag && (n * 16 + fr > wid * 16 + fq * 4 + r)) v = -1e30f;
                sv[n] = __expf(v);
            }
            float ps = (sv[0] + sv[1]) + (sv[2] + sv[3]);
            ps += __shfl_xor(ps, 1);
            ps += __shfl_xor(ps, 2);
            ps += __shfl_xor(ps, 4);
            ps += __shfl_xor(ps, 8);
            lrow[r] += ps;
            #pragma unroll
            for (int n = 0; n < 4; ++n)
                pl[wid][SWZ(fq * 4 + r, n * 16 + fr)] = f2b(sv[n]);
        }

        __builtin_amdgcn_s_setprio(1);
        #pragma unroll
        for (int kk = 0; kk < 2; ++kk) {
            const short8 pa = *reinterpret_cast<const short8*>(
                &pl[wid][SWZ(fr, kk * 32 + fq * 8)]);
            #pragma unroll
            for (int n = 0; n < 4; ++n) {
                const short8 vf = *reinterpret_cast<const short8*>(
                    &vT[cur][SWZ(n * 16 + fr, kk * 32 + fq * 8)]);
                oacc[n] = __builtin_amdgcn_mfma_f32_16x16x32_bf16(pa, vf, oacc[n], 0, 0, 0);
            }
        }
        __builtin_amdgcn_s_setprio(0);
    };

    AT_STAGE(0, 0);
    __syncthreads();

    for (int ch = 0; ch <= qtB; ++ch) {
        const int cur = ch & 1;
        if (ch < qtB) AT_STAGE(cur ^ 1, ch + 1);

        tile_step(cur, qtB, ch, qfB, oaccB, lB_);
        if (ch <= qtA)
            tile_step(cur, qtA, ch, qfA, oaccA, lA_);

        __syncthreads();
    }
    #undef AT_STAGE

    #pragma unroll
    for (int s = 0; s < 2; ++s) {
        const int qt = s ? qtB : qtA;
        const f32x4* oacc = s ? oaccB : oaccA;
        const float* lrow = s ? lB_ : lA_;
        const size_t orow0 = (size_t)b * LL + qt * 64 + wid * 16 + fq * 4;
        #pragma unroll
        for (int r = 0; r < 4; ++r) {
            const float inv = 1.f / lrow[r];
            const size_t rowidx = (orow0 + r) * CHN + hc;
            #pragma unroll
            for (int n = 0; n < 4; ++n) {
                const int d = n * 16 + fr;
                Sout[rowidx + d] = f2b(oacc[n][r] * inv + b2f(Qin[rowidx + d]));
            }
        }
    }
}

// ---------------------------------------------------------------------------
__global__ __launch_bounds__(256) void temb_embed_kernel(
    const int* __restrict__ t, float* __restrict__ T0)
{
    const int idx = blockIdx.x * 256 + threadIdx.x;
    const int b = idx >> 9, j = idx & 511;
    const float tv = (float)t[b];
    const int jj = (j < 256) ? j : j - 256;
    const float freq = __expf((float)jj * (-9.210340371976184f / 255.f));
    const float ang = tv * freq;
    T0[idx] = (j < 256) ? sinf(ang) : cosf(ang);
}

__global__ __launch_bounds__(256) void add_temb_kernel(
    const float* __restrict__ xin, const float* __restrict__ temb,
    unsigned short* __restrict__ out)
{
    const size_t i4 = (size_t)blockIdx.x * 256 + threadIdx.x;
    const size_t elem = i4 * 4;
    const int b = (int)(elem >> 18);
    const int c = (int)(elem & (CHN - 1));
    const float4 a = reinterpret_cast<const float4*>(xin)[i4];
    const float4 tv = *reinterpret_cast<const float4*>(temb + (size_t)b * CHN + c);
    ushort4 o;
    o.x = f2b(a.x + tv.x); o.y = f2b(a.y + tv.y);
    o.z = f2b(a.z + tv.z); o.w = f2b(a.w + tv.w);
    reinterpret_cast<ushort4*>(out)[i4] = o;
}

// ---------------------------------------------------------------------------
extern "C" void kernel_launch(void* const* d_in, const int* in_sizes, int n_in,
                              void* d_out, int out_size, void* d_ws, size_t ws_size,
                              hipStream_t stream)
{
    (void)in_sizes; (void)n_in; (void)out_size; (void)ws_size;
    const float* log_seqs = (const float*)d_in[0];
    const float* seqs_nxt = (const float*)d_in[1];
    const int*   tt       = (const int*)d_in[2];
    const float* qw  = (const float*)d_in[3];
    const float* qb  = (const float*)d_in[4];
    const float* kw  = (const float*)d_in[5];
    const float* kb  = (const float*)d_in[6];
    const float* vw  = (const float*)d_in[7];
    const float* vb  = (const float*)d_in[8];
    const float* ln1g = (const float*)d_in[9];
    const float* ln1b = (const float*)d_in[10];
    const float* ln2g = (const float*)d_in[11];
    const float* ln2b = (const float*)d_in[12];
    const float* c1w = (const float*)d_in[13];
    const float* c1b = (const float*)d_in[14];
    const float* c2w = (const float*)d_in[15];
    const float* c2b = (const float*)d_in[16];
    const float* posK = (const float*)d_in[17];
    const float* posV = (const float*)d_in[18];
    const float* lng = (const float*)d_in[19];
    const float* lnb = (const float*)d_in[20];
    const float* tw0 = (const float*)d_in[21];
    const float* tb0 = (const float*)d_in[22];
    const float* tw1 = (const float*)d_in[23];
    const float* tb1 = (const float*)d_in[24];
    const float* tw2 = (const float*)d_in[25];
    const float* tb2 = (const float*)d_in[26];
    const float* decw = (const float*)d_in[27];
    const float* decb = (const float*)d_in[28];

    const size_t SZ = (size_t)BB * LL * CHN;  // 8388608
    const int M = BB * LL;                    // 16384
    float* out = (float*)d_out;
    float* log_feats = out;
    float* dec = out + SZ;
    unsigned short* QBb = (unsigned short*)dec;        // Q bf16 until decoder
    unsigned short* VTb = (unsigned short*)log_feats;  // V^T bf16 until final LN

    float* ws = (float*)d_ws;
    unsigned short* SB = (unsigned short*)ws;                 // residual stream bf16
    float* P = ws + SZ / 2;                                   // split-K partials
    unsigned short* KBb = (unsigned short*)(ws + SZ);
    unsigned short* R0  = (unsigned short*)(ws + SZ + SZ / 2);
    unsigned short* R1  = (unsigned short*)(ws + 2 * SZ);
    unsigned short* WBu = (unsigned short*)(ws + 2 * SZ + SZ / 2);  // 3145728 bf16
    float* T0 = ws + 2 * SZ + SZ / 2 + 1572864;
    float* T1 = T0 + 32 * CHN;
    float* T2 = T1 + 32 * 2048;
    float* T3 = T2 + 32 * 2048;

    const size_t WQ = 0, WKV = 524288, WC1 = 1572864,
                 WC2 = 2097152, WDEC = 2621440;

    auto mg = [&](const unsigned short* A, const unsigned short* W, int ldw,
                  const float* bias, const float* pos, const unsigned short* resb,
                  float* outf, unsigned short* outb, unsigned short* outbt, int act) {
        mgemm_kernel<<<256, 512, 0, stream>>>(A, W, ldw, bias, pos, resb,
                                              outf, outb, outbt, act);
    };
    auto skg = [&](const float* A, int K, const float* W, int N,
                   const float* bias, float* o, int act) {
        skgemm_kernel<<<dim3(N / 256, K / 128), 256, 0, stream>>>(A, K, W, N, P);
        skreduce_kernel<<<(N * 32) / 256, 256, 0, stream>>>(P, K / 128, bias, o, N, act);
    };

    // weight + input conversions in one launch
    cvt7_kernel<<<dim3(512, 7), 256, 0, stream>>>(qw, kw, vw, c1w, c2w, decw, WBu,
                                                  log_seqs, R1);

    // per layer: R1 -> ln1 -> R0 -> qkv2(Q from R0, KV from R1) -> mattn -> SB
    //            -> ln2(SB in-place) -> c1 -> R0 -> c2(+SB res) -> R1
    for (int i = 0; i < 2; ++i) {
        const size_t wo = (size_t)i * 262144;
        const size_t bo = (size_t)i * CHN;

        ln_kernel<<<M, 256, 0, stream>>>(R1, ln1g + bo, ln1b + bo, nullptr, R0);
        qkv2_kernel<<<768, 512, 0, stream>>>(
            R0, R1, WBu + WQ + wo, WBu + WKV + (size_t)i * 524288,
            qb + bo, kb + bo, vb + bo, posK, posV, QBb, KBb, VTb);
        mattn_kernel<<<dim3(4, NHH, BB), 256, 0, stream>>>(QBb, KBb, VTb, R0, SB);
        ln_kernel<<<M, 256, 0, stream>>>(SB, ln2g + bo, ln2b + bo, nullptr, SB);
        mg(SB, WBu + WC1 + wo, 512, c1b + bo, nullptr, nullptr, nullptr, R0, nullptr, 1);
        mg(R0, WBu + WC2 + wo, 512, c2b + bo, nullptr, SB, nullptr, R1, nullptr, 0);
    }

    ln_kernel<<<M, 256, 0, stream>>>(R1, lng, lnb, log_feats, R0);

    temb_embed_kernel<<<(BB * CHN) / 256, 256, 0, stream>>>(tt, T0);
    skg(T0, 512, tw0, 2048, tb0, T1, 2);
    skg(T1, 2048, tw1, 2048, tb1, T2, 2);
    skg(T2, 2048, tw2, 512, tb2, T3, 0);
    add_temb_kernel<<<(M * CHN / 4) / 256, 256, 0, stream>>>(seqs_nxt, T3, R1);

    dec_kernel<<<256, 512, 0, stream>>>(R0, R1, WBu + WDEC, decb, dec);
}

// Round 18
// 591.266 us; speedup vs baseline: 1.1081x; 1.0087x over previous
//
#include <hip/hip_runtime.h>
#include <math.h>

#define BB 32
#define LL 512
#define CHN 512
#define NHH 8
#define HDD 64

typedef __attribute__((ext_vector_type(8))) short short8;
typedef __attribute__((ext_vector_type(4))) float f32x4;

__device__ __forceinline__ float b2f(unsigned short s) {
    union { unsigned int u; float f; } c; c.u = ((unsigned int)s) << 16; return c.f;
}
__device__ __forceinline__ unsigned short f2b(float f) {
    union { float f; unsigned int u; } c; c.f = f;
    return (unsigned short)((c.u + 0x7fffu + ((c.u >> 16) & 1u)) >> 16);
}

// swizzled ushort index for a [rows][64] bf16 LDS tile (breaks 128B-stride conflicts)
#define SWZ(row, col) ((((row) * 64 + (col))) ^ (((row) & 7) << 3))

__device__ __forceinline__ void gl16(const unsigned short* g, unsigned short* l) {
    __builtin_amdgcn_global_load_lds(
        (const __attribute__((address_space(1))) unsigned int*)g,
        (__attribute__((address_space(3))) unsigned int*)l, 16, 0, 0);
}

// ---------------------------------------------------------------------------
// Weight slab (bf16 ushorts):
//   [0,524288)          qw  L0,L1
//   [524288,1572864)    KV: per layer contiguous [kw_i(512x512); vw_i(512x512)]
//   [1572864,2097152)   c1w L0,L1
//   [2097152,2621440)   c2w L0,L1
//   [2621440,3145728)   decw
// cvt7 also converts log_seqs -> R1.
// ---------------------------------------------------------------------------
__global__ __launch_bounds__(256) void cvt7_kernel(
    const float* __restrict__ p0, const float* __restrict__ p1,
    const float* __restrict__ p2, const float* __restrict__ p3,
    const float* __restrict__ p4, const float* __restrict__ p5,
    unsigned short* __restrict__ y,
    const float* __restrict__ seqs, unsigned short* __restrict__ R1)
{
    const int j = blockIdx.y;
    const int i = blockIdx.x * 256 + threadIdx.x;   // 0..131071 (float4 units)
    if (j < 6) {
        const float* x = j == 0 ? p0 : j == 1 ? p1 : j == 2 ? p2
                       : j == 3 ? p3 : j == 4 ? p4 : p5;
        const float4 v = reinterpret_cast<const float4*>(x)[i];
        ushort4 o;
        o.x = f2b(v.x); o.y = f2b(v.y); o.z = f2b(v.z); o.w = f2b(v.w);
        size_t dst4;
        if (j == 1)      dst4 = 131072 + i + (i >= 65536 ? 65536 : 0);          // kw
        else if (j == 2) dst4 = 131072 + 65536 + i + (i >= 65536 ? 65536 : 0);  // vw
        else             dst4 = (size_t)j * 131072 + i;  // qw(0), c1(3), c2(4), dec(5)
        reinterpret_cast<ushort4*>(y)[dst4] = o;
    } else {
        #pragma unroll
        for (int t = 0; t < 16; ++t) {
            const int ii = t * 131072 + i;
            const float4 v = reinterpret_cast<const float4*>(seqs)[ii];
            ushort4 o;
            o.x = f2b(v.x); o.y = f2b(v.y); o.z = f2b(v.z); o.w = f2b(v.w);
            reinterpret_cast<ushort4*>(R1)[ii] = o;
        }
    }
}

// ---------------------------------------------------------------------------
// Row LayerNorm over CH=512 (eps=1e-8), bf16 input, f32 stats.
// ---------------------------------------------------------------------------
__global__ __launch_bounds__(256) void ln_kernel(
    const unsigned short* __restrict__ x, const float* __restrict__ g,
    const float* __restrict__ b, float* __restrict__ yf,
    unsigned short* __restrict__ yb)
{
    const int row = blockIdx.x;
    const int tid = threadIdx.x;
    const size_t base = (size_t)row * CHN;
    const ushort2 v2 = *reinterpret_cast<const ushort2*>(x + base + tid * 2);
    const float vx = b2f(v2.x), vy = b2f(v2.y);
    float s  = vx + vy;
    float ss = vx * vx + vy * vy;
    #pragma unroll
    for (int m = 1; m < 64; m <<= 1) {
        s  += __shfl_xor(s, m);
        ss += __shfl_xor(ss, m);
    }
    __shared__ float red[8];
    const int wave = tid >> 6;
    if ((tid & 63) == 0) { red[wave] = s; red[4 + wave] = ss; }
    __syncthreads();
    s  = red[0] + red[1] + red[2] + red[3];
    ss = red[4] + red[5] + red[6] + red[7];
    const float mean = s * (1.0f / CHN);
    const float var  = ss * (1.0f / CHN) - mean * mean;
    const float inv  = rsqrtf(var + 1e-8f);
    const int c = tid * 2;
    float ox = (vx - mean) * inv * g[c]     + b[c];
    float oy = (vy - mean) * inv * g[c + 1] + b[c + 1];
    if (yf) *reinterpret_cast<float2*>(yf + base + c) = make_float2(ox, oy);
    if (yb) {
        ushort2 ob; ob.x = f2b(ox); ob.y = f2b(oy);
        *reinterpret_cast<ushort2*>(yb + base + c) = ob;
    }
}

// ---------------------------------------------------------------------------
// bf16 MFMA GEMM body (depth-3, measured-best): 256x128 tile, BK=32,
// 8 waves (4x2). NBX = N/128 tiles. act: 0=none 1=relu 3=scale-by-0.125.
// ---------------------------------------------------------------------------
template <int NT, int NBX>
__device__ __forceinline__ void gemm_body(
    const unsigned short* __restrict__ A,
    const unsigned short* __restrict__ A2,
    const unsigned short* __restrict__ W, int ldw,
    const float* __restrict__ bias,
    const float* __restrict__ pos,
    const unsigned short* __restrict__ resb,
    float* __restrict__ outf,
    unsigned short* __restrict__ outb,
    unsigned short* __restrict__ outbt,
    int act, int bid,
    unsigned short* lA, unsigned short* lB)
{
    const int tid  = threadIdx.x;
    const int lane = tid & 63;
    const int wid  = tid >> 6;          // 0..7

    const int swz = (bid & 7) * (NBX * 8) + (bid >> 3);
    const int by = swz / NBX, bx = swz % NBX;
    const int bm = by * 256, bn = bx * 128;

    const int ia0 = wid * 2, ia1 = wid * 2 + 1;
    const int hiA0 = ia0 >> 2, rgA0 = ia0 & 3;
    const int hiA1 = ia1 >> 2, rgA1 = ia1 & 3;
    const int hiB = wid >> 1, rgB = wid & 1;

    const unsigned short* Ax = A2 ? A2 : A;
    const unsigned short* aS0  = A  + (size_t)(bm + rgA0 * 64 + lane) * 512 + hiA0 * 8;
    const unsigned short* aS1  = A  + (size_t)(bm + rgA1 * 64 + lane) * 512 + hiA1 * 8;
    const unsigned short* a2S0 = Ax + (size_t)(bm + rgA0 * 64 + lane) * 512 + hiA0 * 8;
    const unsigned short* a2S1 = Ax + (size_t)(bm + rgA1 * 64 + lane) * 512 + hiA1 * 8;
    const unsigned short* wS   = W + (size_t)(bn + rgB * 64 + lane) * ldw + hiB * 8;
    const int dA0 = (hiA0 * 256 + rgA0 * 64) * 8;
    const int dA1 = (hiA1 * 256 + rgA1 * 64) * 8;
    const int dB  = (hiB * 128 + rgB * 64) * 8;

    const int wr = wid >> 1, wc = wid & 1;
    const int fr = lane & 15;
    const int fq = lane >> 4;

    f32x4 acc[4][4];
    #pragma unroll
    for (int m = 0; m < 4; ++m)
        #pragma unroll
        for (int n = 0; n < 4; ++n)
            acc[m][n] = (f32x4){0.f, 0.f, 0.f, 0.f};

    #define MG_STAGE(buf, t)                                            \
        do {                                                            \
            const int k0 = ((t) & 15) * 32;                             \
            const unsigned short* s0 = ((t) < 16) ? aS0 : a2S0;         \
            const unsigned short* s1 = ((t) < 16) ? aS1 : a2S1;         \
            gl16(s0 + k0, &lA[(buf) * 8192 + dA0]);                     \
            gl16(s1 + k0, &lA[(buf) * 8192 + dA1]);                     \
            gl16(wS + (t) * 32, &lB[(buf) * 4096 + dB]);                \
        } while (0)

    MG_STAGE(0, 0);
    MG_STAGE(1, 1);

    #pragma unroll
    for (int t = 0; t < NT; ++t) {
        const int cur = t % 3;
        if (t + 2 < NT) {
            MG_STAGE((t + 2) % 3, t + 2);
            asm volatile("s_waitcnt vmcnt(6)" ::: "memory");
        } else if (t + 1 < NT) {
            asm volatile("s_waitcnt vmcnt(3)" ::: "memory");
        } else {
            asm volatile("s_waitcnt vmcnt(0)" ::: "memory");
        }
        __builtin_amdgcn_s_barrier();

        const unsigned short* pa = &lA[cur * 8192 + (fq * 256 + wr * 64 + fr) * 8];
        const unsigned short* pb = &lB[cur * 4096 + (fq * 128 + wc * 64 + fr) * 8];
        short8 aF[4], bF[4];
        #pragma unroll
        for (int m = 0; m < 4; ++m)
            aF[m] = *reinterpret_cast<const short8*>(pa + m * 128);
        #pragma unroll
        for (int n = 0; n < 4; ++n)
            bF[n] = *reinterpret_cast<const short8*>(pb + n * 128);
        asm volatile("s_waitcnt lgkmcnt(0)" ::: "memory");
        __builtin_amdgcn_s_barrier();

        __builtin_amdgcn_s_setprio(1);
        #pragma unroll
        for (int m = 0; m < 4; ++m)
            #pragma unroll
            for (int n = 0; n < 4; ++n)
                acc[m][n] = __builtin_amdgcn_mfma_f32_16x16x32_bf16(
                    aF[m], bF[n], acc[m][n], 0, 0, 0);
        __builtin_amdgcn_s_setprio(0);
    }
    #undef MG_STAGE

    const int row0 = bm + wr * 64, col0 = bn + wc * 64;
    #pragma unroll
    for (int m = 0; m < 4; ++m) {
        #pragma unroll
        for (int n = 0; n < 4; ++n) {
            const int col = col0 + n * 16 + fr;
            const float bia = bias ? bias[col] : 0.f;
            ushort4 o4;
            #pragma unroll
            for (int r = 0; r < 4; ++r) {
                const int row = row0 + m * 16 + fq * 4 + r;
                float v = acc[m][n][r] + bia;
                if (pos) v += pos[(size_t)(row & (LL - 1)) * CHN + col];
                if (act == 1) v = fmaxf(v, 0.f);
                else if (act == 3) v *= 0.125f;
                const size_t idx = (size_t)row * CHN + col;
                if (resb) v += b2f(resb[idx]);
                if (outf) outf[idx] = v;
                if (outb) outb[idx] = f2b(v);
                ((unsigned short*)&o4)[r] = f2b(v);
            }
            if (outbt) {
                const int rw = row0 + m * 16 + fq * 4;
                *reinterpret_cast<ushort4*>(
                    &outbt[((size_t)(rw >> 9) * 512 + col) * 512 + (rw & 511)]) = o4;
            }
        }
    }
}

// ---------------------------------------------------------------------------
// KV body: N=1024 GEMM over W_kv = [kw;vw], depth-3. Block-uniform epilogue
// split: bn<512 -> K (posK, KBb); bn>=512 -> V (posV, VTb transposed).
// ---------------------------------------------------------------------------
__device__ __forceinline__ void kv_body(
    const unsigned short* __restrict__ A,
    const unsigned short* __restrict__ Wkv,
    const float* __restrict__ kb, const float* __restrict__ vb,
    const float* __restrict__ posK, const float* __restrict__ posV,
    unsigned short* __restrict__ KBb, unsigned short* __restrict__ VTb,
    int bid, unsigned short* lA, unsigned short* lB)
{
    const int tid  = threadIdx.x;
    const int lane = tid & 63;
    const int wid  = tid >> 6;

    const int swz = (bid & 7) * 64 + (bid >> 3);   // 512 blocks
    const int by = swz >> 3, bx = swz & 7;
    const int bm = by * 256, bn = bx * 128;

    const int ia0 = wid * 2, ia1 = wid * 2 + 1;
    const int hiA0 = ia0 >> 2, rgA0 = ia0 & 3;
    const int hiA1 = ia1 >> 2, rgA1 = ia1 & 3;
    const int hiB = wid >> 1, rgB = wid & 1;

    const unsigned short* aS0 = A + (size_t)(bm + rgA0 * 64 + lane) * 512 + hiA0 * 8;
    const unsigned short* aS1 = A + (size_t)(bm + rgA1 * 64 + lane) * 512 + hiA1 * 8;
    const unsigned short* wS  = Wkv + (size_t)(bn + rgB * 64 + lane) * 512 + hiB * 8;
    const int dA0 = (hiA0 * 256 + rgA0 * 64) * 8;
    const int dA1 = (hiA1 * 256 + rgA1 * 64) * 8;
    const int dB  = (hiB * 128 + rgB * 64) * 8;

    const int wr = wid >> 1, wc = wid & 1;
    const int fr = lane & 15;
    const int fq = lane >> 4;

    f32x4 acc[4][4];
    #pragma unroll
    for (int m = 0; m < 4; ++m)
        #pragma unroll
        for (int n = 0; n < 4; ++n)
            acc[m][n] = (f32x4){0.f, 0.f, 0.f, 0.f};

    #define KV_STAGE(buf, t)                                            \
        do {                                                            \
            const int k0 = (t) * 32;                                    \
            gl16(aS0 + k0, &lA[(buf) * 8192 + dA0]);                    \
            gl16(aS1 + k0, &lA[(buf) * 8192 + dA1]);                    \
            gl16(wS + k0, &lB[(buf) * 4096 + dB]);                      \
        } while (0)

    KV_STAGE(0, 0);
    KV_STAGE(1, 1);

    #pragma unroll
    for (int t = 0; t < 16; ++t) {
        const int cur = t % 3;
        if (t + 2 < 16) {
            KV_STAGE((t + 2) % 3, t + 2);
            asm volatile("s_waitcnt vmcnt(6)" ::: "memory");
        } else if (t + 1 < 16) {
            asm volatile("s_waitcnt vmcnt(3)" ::: "memory");
        } else {
            asm volatile("s_waitcnt vmcnt(0)" ::: "memory");
        }
        __builtin_amdgcn_s_barrier();

        const unsigned short* pa = &lA[cur * 8192 + (fq * 256 + wr * 64 + fr) * 8];
        const unsigned short* pb = &lB[cur * 4096 + (fq * 128 + wc * 64 + fr) * 8];
        short8 aF[4], bF[4];
        #pragma unroll
        for (int m = 0; m < 4; ++m)
            aF[m] = *reinterpret_cast<const short8*>(pa + m * 128);
        #pragma unroll
        for (int n = 0; n < 4; ++n)
            bF[n] = *reinterpret_cast<const short8*>(pb + n * 128);
        asm volatile("s_waitcnt lgkmcnt(0)" ::: "memory");
        __builtin_amdgcn_s_barrier();

        __builtin_amdgcn_s_setprio(1);
        #pragma unroll
        for (int m = 0; m < 4; ++m)
            #pragma unroll
            for (int n = 0; n < 4; ++n)
                acc[m][n] = __builtin_amdgcn_mfma_f32_16x16x32_bf16(
                    aF[m], bF[n], acc[m][n], 0, 0, 0);
        __builtin_amdgcn_s_setprio(0);
    }
    #undef KV_STAGE

    const int row0 = bm + wr * 64;
    if (bn < 512) {
        const int col0 = bn + wc * 64;
        #pragma unroll
        for (int m = 0; m < 4; ++m) {
            #pragma unroll
            for (int n = 0; n < 4; ++n) {
                const int col = col0 + n * 16 + fr;
                const float bia = kb[col];
                #pragma unroll
                for (int r = 0; r < 4; ++r) {
                    const int row = row0 + m * 16 + fq * 4 + r;
                    float v = acc[m][n][r] + bia
                            + posK[(size_t)(row & (LL - 1)) * CHN + col];
                    KBb[(size_t)row * CHN + col] = f2b(v);
                }
            }
        }
    } else {
        const int vcol0 = (bn - 512) + wc * 64;
        #pragma unroll
        for (int m = 0; m < 4; ++m) {
            #pragma unroll
            for (int n = 0; n < 4; ++n) {
                const int vcol = vcol0 + n * 16 + fr;
                const float bia = vb[vcol];
                ushort4 o4;
                #pragma unroll
                for (int r = 0; r < 4; ++r) {
                    const int row = row0 + m * 16 + fq * 4 + r;
                    float v = acc[m][n][r] + bia
                            + posV[(size_t)(row & (LL - 1)) * CHN + vcol];
                    ((unsigned short*)&o4)[r] = f2b(v);
                }
                const int rw = row0 + m * 16 + fq * 4;
                *reinterpret_cast<ushort4*>(
                    &VTb[((size_t)(rw >> 9) * 512 + vcol) * 512 + (rw & 511)]) = o4;
            }
        }
    }
}

__global__ __launch_bounds__(512) void mgemm_kernel(
    const unsigned short* __restrict__ A,
    const unsigned short* __restrict__ W, int ldw,
    const float* __restrict__ bias,
    const float* __restrict__ pos,
    const unsigned short* __restrict__ resb,
    float* __restrict__ outf,
    unsigned short* __restrict__ outb,
    unsigned short* __restrict__ outbt,
    int act)
{
    __shared__ alignas(16) unsigned short lA[3 * 8192];
    __shared__ alignas(16) unsigned short lB[3 * 4096];
    gemm_body<16, 4>(A, nullptr, W, ldw, bias, pos, resb, outf, outb, outbt, act,
                     blockIdx.x, lA, lB);
}

// Fused Q + KV: blocks 0-255 = Q GEMM (A=qinb), 256-767 = KV GEMM (A=curb).
__global__ __launch_bounds__(512) void qkv2_kernel(
    const unsigned short* __restrict__ qinb, const unsigned short* __restrict__ curb,
    const unsigned short* __restrict__ Wq, const unsigned short* __restrict__ Wkv,
    const float* __restrict__ qb, const float* __restrict__ kb,
    const float* __restrict__ vb,
    const float* __restrict__ posK, const float* __restrict__ posV,
    unsigned short* __restrict__ QBb, unsigned short* __restrict__ KBb,
    unsigned short* __restrict__ VTb)
{
    __shared__ alignas(16) unsigned short lA[3 * 8192];
    __shared__ alignas(16) unsigned short lB[3 * 4096];
    if (blockIdx.x < 256) {
        gemm_body<16, 4>(qinb, nullptr, Wq, 512, qb, nullptr, nullptr,
                         nullptr, QBb, nullptr, 3, blockIdx.x, lA, lB);
    } else {
        kv_body(curb, Wkv, kb, vb, posK, posV, KBb, VTb, blockIdx.x - 256, lA, lB);
    }
}

// Decoder fused: dec = [log_feats | x_t] @ decw^T + decb  (K=1024, two A sources)
__global__ __launch_bounds__(512) void dec_kernel(
    const unsigned short* __restrict__ R0b, const unsigned short* __restrict__ R1b,
    const unsigned short* __restrict__ Wd, const float* __restrict__ decb,
    float* __restrict__ dec)
{
    __shared__ alignas(16) unsigned short lA[3 * 8192];
    __shared__ alignas(16) unsigned short lB[3 * 4096];
    gemm_body<32, 4>(R0b, R1b, Wd, 1024, decb, nullptr, nullptr, dec, nullptr,
                     nullptr, 0, blockIdx.x, lA, lB);
}

// ---------------------------------------------------------------------------
// Split-K small-M GEMM for the temb path.
// ---------------------------------------------------------------------------
__global__ __launch_bounds__(256) void skgemm_kernel(
    const float* __restrict__ A, int K,
    const float* __restrict__ W, int N,
    float* __restrict__ P)
{
    __shared__ float As[32][128];
    const int tid = threadIdx.x;
    const int kz  = blockIdx.y;
    const int c   = blockIdx.x * 256 + tid;

    #pragma unroll
    for (int i = 0; i < 16; ++i) {
        const int idx = i * 256 + tid;
        const int r = idx >> 7, k = idx & 127;
        As[r][k] = A[(size_t)r * K + kz * 128 + k];
    }
    __syncthreads();

    float acc[32];
    #pragma unroll
    for (int r = 0; r < 32; ++r) acc[r] = 0.f;

    const float* wrow = W + (size_t)c * K + kz * 128;
    for (int k4 = 0; k4 < 32; ++k4) {
        const float4 w = reinterpret_cast<const float4*>(wrow)[k4];
        #pragma unroll
        for (int r = 0; r < 32; ++r) {
            const float4 a = *reinterpret_cast<const float4*>(&As[r][k4 * 4]);
            acc[r] = fmaf(w.x, a.x, fmaf(w.y, a.y, fmaf(w.z, a.z, fmaf(w.w, a.w, acc[r]))));
        }
    }

    float* pp = P + ((size_t)kz * N + c) * 32;
    #pragma unroll
    for (int r = 0; r < 32; ++r) pp[r] = acc[r];
}

__global__ __launch_bounds__(256) void skreduce_kernel(
    const float* __restrict__ P, int KS, const float* __restrict__ bias,
    float* __restrict__ out, int N, int act)
{
    const int idx = blockIdx.x * 256 + threadIdx.x;
    const int r = idx & 31, c = idx >> 5;
    float s = 0.f;
    for (int kz = 0; kz < KS; ++kz)
        s += P[(size_t)kz * N * 32 + idx];
    s += bias[c];
    if (act == 2) s = s / (1.f + __expf(-s));
    out[(size_t)r * N + c] = s;
}

// ---------------------------------------------------------------------------
// MFMA causal flash attention, paired q-tiles on PARALLEL wave-groups:
// 512 threads / 8 waves; group 0 (waves 0-3) computes tile qtB, group 1
// (waves 4-7) computes tile qtA concurrently on shared staged K/V chunks.
// Fixed-base softmax. Block pr handles (pr, 7-pr). Sout bf16.
// ---------------------------------------------------------------------------
__global__ __launch_bounds__(512) void mattn_kernel(
    const unsigned short* __restrict__ Q, const unsigned short* __restrict__ K,
    const unsigned short* __restrict__ VT, const unsigned short* __restrict__ Qin,
    unsigned short* __restrict__ Sout)
{
    __shared__ alignas(16) unsigned short kT[2][4096];
    __shared__ alignas(16) unsigned short vT[2][4096];
    __shared__ unsigned short pl[8][1024];

    const int pr = blockIdx.x;          // 0..3
    const int qtA = pr, qtB = 7 - pr;
    const int h  = blockIdx.y;
    const int b  = blockIdx.z;
    const int tid = threadIdx.x, lane = tid & 63, wid = tid >> 6;   // wid 0..7
    const int wg = wid >> 2;            // wave-group: 0 -> qtB, 1 -> qtA
    const int wl = wid & 3;             // wave-local index within group
    const int fr = lane & 15, fq = lane >> 4;
    const int hc = h * HDD;

    // staging: one K-chunk piece + one V-chunk piece per thread (512 x 16B each)
    const int rs = tid >> 3, js = tid & 7, ds = ((js ^ (rs & 7)) << 3);
    const unsigned short* kS = K + (size_t)b * LL * CHN + (size_t)rs * CHN + hc + ds;
    const unsigned short* vS = VT + ((size_t)(b * NHH + h) * 64 + rs) * 512 + ds;

    #define AT_STAGE(buf, ch)                                              \
        do {                                                               \
            const int o = (ch) * 64;                                       \
            gl16(kS + (size_t)o * CHN, &kT[buf][wid * 512]);               \
            gl16(vS + o, &vT[buf][wid * 512]);                             \
        } while (0)

    // Q fragments for this group's tile: row = fr, k = kk*32 + fq*8
    const int myQt = wg ? qtA : qtB;
    const size_t qrow = (size_t)b * LL + myQt * 64 + wl * 16 + fr;
    short8 qf[2];
    qf[0] = *reinterpret_cast<const short8*>(Q + qrow * CHN + hc + fq * 8);
    qf[1] = *reinterpret_cast<const short8*>(Q + qrow * CHN + hc + 32 + fq * 8);

    f32x4 oacc[4];
    float lrow[4];
    #pragma unroll
    for (int n = 0; n < 4; ++n) oacc[n] = (f32x4){0.f, 0.f, 0.f, 0.f};
    #pragma unroll
    for (int r = 0; r < 4; ++r) lrow[r] = 0.f;

    AT_STAGE(0, 0);
    __syncthreads();

    for (int ch = 0; ch <= qtB; ++ch) {
        const int cur = ch & 1;
        if (ch < qtB) AT_STAGE(cur ^ 1, ch + 1);

        if (ch <= myQt) {
            // QK^T
            f32x4 sacc[4];
            #pragma unroll
            for (int n = 0; n < 4; ++n) sacc[n] = (f32x4){0.f, 0.f, 0.f, 0.f};
            __builtin_amdgcn_s_setprio(1);
            #pragma unroll
            for (int kk = 0; kk < 2; ++kk) {
                #pragma unroll
                for (int n = 0; n < 4; ++n) {
                    const short8 kf = *reinterpret_cast<const short8*>(
                        &kT[cur][SWZ(n * 16 + fr, kk * 32 + fq * 8)]);
                    sacc[n] = __builtin_amdgcn_mfma_f32_16x16x32_bf16(
                        qf[kk], kf, sacc[n], 0, 0, 0);
                }
            }
            __builtin_amdgcn_s_setprio(0);

            // fixed-base softmax
            const bool diag = (ch == myQt);
            #pragma unroll
            for (int r = 0; r < 4; ++r) {
                float sv[4];
                #pragma unroll
                for (int n = 0; n < 4; ++n) {
                    float v = sacc[n][r];
                    if (diag && (n * 16 + fr > wl * 16 + fq * 4 + r)) v = -1e30f;
                    sv[n] = __expf(v);
                }
                float ps = (sv[0] + sv[1]) + (sv[2] + sv[3]);
                ps += __shfl_xor(ps, 1);
                ps += __shfl_xor(ps, 2);
                ps += __shfl_xor(ps, 4);
                ps += __shfl_xor(ps, 8);
                lrow[r] += ps;
                #pragma unroll
                for (int n = 0; n < 4; ++n)
                    pl[wid][SWZ(fq * 4 + r, n * 16 + fr)] = f2b(sv[n]);
            }

            // PV
            __builtin_amdgcn_s_setprio(1);
            #pragma unroll
            for (int kk = 0; kk < 2; ++kk) {
                const short8 pa = *reinterpret_cast<const short8*>(
                    &pl[wid][SWZ(fr, kk * 32 + fq * 8)]);
                #pragma unroll
                for (int n = 0; n < 4; ++n) {
                    const short8 vf = *reinterpret_cast<const short8*>(
                        &vT[cur][SWZ(n * 16 + fr, kk * 32 + fq * 8)]);
                    oacc[n] = __builtin_amdgcn_mfma_f32_16x16x32_bf16(
                        pa, vf, oacc[n], 0, 0, 0);
                }
            }
            __builtin_amdgcn_s_setprio(0);
        }

        __syncthreads();  // all reads of kT/vT[cur] done; next stage may land
    }
    #undef AT_STAGE

    // epilogue for this group's tile
    const size_t orow0 = (size_t)b * LL + myQt * 64 + wl * 16 + fq * 4;
    #pragma unroll
    for (int r = 0; r < 4; ++r) {
        const float inv = 1.f / lrow[r];
        const size_t rowidx = (orow0 + r) * CHN + hc;
        #pragma unroll
        for (int n = 0; n < 4; ++n) {
            const int d = n * 16 + fr;
            Sout[rowidx + d] = f2b(oacc[n][r] * inv + b2f(Qin[rowidx + d]));
        }
    }
}

// ---------------------------------------------------------------------------
__global__ __launch_bounds__(256) void temb_embed_kernel(
    const int* __restrict__ t, float* __restrict__ T0)
{
    const int idx = blockIdx.x * 256 + threadIdx.x;
    const int b = idx >> 9, j = idx & 511;
    const float tv = (float)t[b];
    const int jj = (j < 256) ? j : j - 256;
    const float freq = __expf((float)jj * (-9.210340371976184f / 255.f));
    const float ang = tv * freq;
    T0[idx] = (j < 256) ? sinf(ang) : cosf(ang);
}

__global__ __launch_bounds__(256) void add_temb_kernel(
    const float* __restrict__ xin, const float* __restrict__ temb,
    unsigned short* __restrict__ out)
{
    const size_t i4 = (size_t)blockIdx.x * 256 + threadIdx.x;
    const size_t elem = i4 * 4;
    const int b = (int)(elem >> 18);
    const int c = (int)(elem & (CHN - 1));
    const float4 a = reinterpret_cast<const float4*>(xin)[i4];
    const float4 tv = *reinterpret_cast<const float4*>(temb + (size_t)b * CHN + c);
    ushort4 o;
    o.x = f2b(a.x + tv.x); o.y = f2b(a.y + tv.y);
    o.z = f2b(a.z + tv.z); o.w = f2b(a.w + tv.w);
    reinterpret_cast<ushort4*>(out)[i4] = o;
}

// ---------------------------------------------------------------------------
extern "C" void kernel_launch(void* const* d_in, const int* in_sizes, int n_in,
                              void* d_out, int out_size, void* d_ws, size_t ws_size,
                              hipStream_t stream)
{
    (void)in_sizes; (void)n_in; (void)out_size; (void)ws_size;
    const float* log_seqs = (const float*)d_in[0];
    const float* seqs_nxt = (const float*)d_in[1];
    const int*   tt       = (const int*)d_in[2];
    const float* qw  = (const float*)d_in[3];
    const float* qb  = (const float*)d_in[4];
    const float* kw  = (const float*)d_in[5];
    const float* kb  = (const float*)d_in[6];
    const float* vw  = (const float*)d_in[7];
    const float* vb  = (const float*)d_in[8];
    const float* ln1g = (const float*)d_in[9];
    const float* ln1b = (const float*)d_in[10];
    const float* ln2g = (const float*)d_in[11];
    const float* ln2b = (const float*)d_in[12];
    const float* c1w = (const float*)d_in[13];
    const float* c1b = (const float*)d_in[14];
    const float* c2w = (const float*)d_in[15];
    const float* c2b = (const float*)d_in[16];
    const float* posK = (const float*)d_in[17];
    const float* posV = (const float*)d_in[18];
    const float* lng = (const float*)d_in[19];
    const float* lnb = (const float*)d_in[20];
    const float* tw0 = (const float*)d_in[21];
    const float* tb0 = (const float*)d_in[22];
    const float* tw1 = (const float*)d_in[23];
    const float* tb1 = (const float*)d_in[24];
    const float* tw2 = (const float*)d_in[25];
    const float* tb2 = (const float*)d_in[26];
    const float* decw = (const float*)d_in[27];
    const float* decb = (const float*)d_in[28];

    const size_t SZ = (size_t)BB * LL * CHN;  // 8388608
    const int M = BB * LL;                    // 16384
    float* out = (float*)d_out;
    float* log_feats = out;
    float* dec = out + SZ;
    unsigned short* QBb = (unsigned short*)dec;        // Q bf16 until decoder
    unsigned short* VTb = (unsigned short*)log_feats;  // V^T bf16 until final LN

    float* ws = (float*)d_ws;
    unsigned short* SB = (unsigned short*)ws;                 // residual stream bf16
    float* P = ws + SZ / 2;                                   // split-K partials
    unsigned short* KBb = (unsigned short*)(ws + SZ);
    unsigned short* R0  = (unsigned short*)(ws + SZ + SZ / 2);
    unsigned short* R1  = (unsigned short*)(ws + 2 * SZ);
    unsigned short* WBu = (unsigned short*)(ws + 2 * SZ + SZ / 2);  // 3145728 bf16
    float* T0 = ws + 2 * SZ + SZ / 2 + 1572864;
    float* T1 = T0 + 32 * CHN;
    float* T2 = T1 + 32 * 2048;
    float* T3 = T2 + 32 * 2048;

    const size_t WQ = 0, WKV = 524288, WC1 = 1572864,
                 WC2 = 2097152, WDEC = 2621440;

    auto mg = [&](const unsigned short* A, const unsigned short* W, int ldw,
                  const float* bias, const float* pos, const unsigned short* resb,
                  float* outf, unsigned short* outb, unsigned short* outbt, int act) {
        mgemm_kernel<<<256, 512, 0, stream>>>(A, W, ldw, bias, pos, resb,
                                              outf, outb, outbt, act);
    };
    auto skg = [&](const float* A, int K, const float* W, int N,
                   const float* bias, float* o, int act) {
        skgemm_kernel<<<dim3(N / 256, K / 128), 256, 0, stream>>>(A, K, W, N, P);
        skreduce_kernel<<<(N * 32) / 256, 256, 0, stream>>>(P, K / 128, bias, o, N, act);
    };

    // weight + input conversions in one launch
    cvt7_kernel<<<dim3(512, 7), 256, 0, stream>>>(qw, kw, vw, c1w, c2w, decw, WBu,
                                                  log_seqs, R1);

    // per layer: R1 -> ln1 -> R0 -> qkv2(Q from R0, KV from R1) -> mattn -> SB
    //            -> ln2(SB in-place) -> c1 -> R0 -> c2(+SB res) -> R1
    for (int i = 0; i < 2; ++i) {
        const size_t wo = (size_t)i * 262144;
        const size_t bo = (size_t)i * CHN;

        ln_kernel<<<M, 256, 0, stream>>>(R1, ln1g + bo, ln1b + bo, nullptr, R0);
        qkv2_kernel<<<768, 512, 0, stream>>>(
            R0, R1, WBu + WQ + wo, WBu + WKV + (size_t)i * 524288,
            qb + bo, kb + bo, vb + bo, posK, posV, QBb, KBb, VTb);
        mattn_kernel<<<dim3(4, NHH, BB), 512, 0, stream>>>(QBb, KBb, VTb, R0, SB);
        ln_kernel<<<M, 256, 0, stream>>>(SB, ln2g + bo, ln2b + bo, nullptr, SB);
        mg(SB, WBu + WC1 + wo, 512, c1b + bo, nullptr, nullptr, nullptr, R0, nullptr, 1);
        mg(R0, WBu + WC2 + wo, 512, c2b + bo, nullptr, SB, nullptr, R1, nullptr, 0);
    }

    ln_kernel<<<M, 256, 0, stream>>>(R1, lng, lnb, log_feats, R0);

    temb_embed_kernel<<<(BB * CHN) / 256, 256, 0, stream>>>(tt, T0);
    skg(T0, 512, tw0, 2048, tb0, T1, 2);
    skg(T1, 2048, tw1, 2048, tb1, T2, 2);
    skg(T2, 2048, tw2, 512, tb2, T3, 0);
    add_temb_kernel<<<(M * CHN / 4) / 256, 256, 0, stream>>>(seqs_nxt, T3, R1);

    dec_kernel<<<256, 512, 0, stream>>>(R0, R1, WBu + WDEC, decb, dec);
}

// Round 19
// 582.035 us; speedup vs baseline: 1.1256x; 1.0159x over previous
//
#include <hip/hip_runtime.h>
#include <math.h>

#define BB 32
#define LL 512
#define CHN 512
#define NHH 8
#define HDD 64

typedef __attribute__((ext_vector_type(8))) short short8;
typedef __attribute__((ext_vector_type(4))) float f32x4;

__device__ __forceinline__ float b2f(unsigned short s) {
    union { unsigned int u; float f; } c; c.u = ((unsigned int)s) << 16; return c.f;
}
__device__ __forceinline__ unsigned short f2b(float f) {
    union { float f; unsigned int u; } c; c.f = f;
    return (unsigned short)((c.u + 0x7fffu + ((c.u >> 16) & 1u)) >> 16);
}

// swizzled ushort index for a [rows][64] bf16 LDS tile (breaks 128B-stride conflicts)
#define SWZ(row, col) ((((row) * 64 + (col))) ^ (((row) & 7) << 3))

__device__ __forceinline__ void gl16(const unsigned short* g, unsigned short* l) {
    __builtin_amdgcn_global_load_lds(
        (const __attribute__((address_space(1))) unsigned int*)g,
        (__attribute__((address_space(3))) unsigned int*)l, 16, 0, 0);
}

// ---------------------------------------------------------------------------
// Piggyback job descriptor: temb-path work appended to host launches.
// kind: 0 none, 1 skgemm (P[kz][c][r32] = A32xK @ W), 2 skreduce, 3 add_temb
// ---------------------------------------------------------------------------
struct XJob {
    int kind;
    const float* a;         // skgemm A | skreduce P | add_temb xin
    const float* w;         // skgemm W | skreduce bias | add_temb temb
    float* o;               // skgemm P | skreduce out
    unsigned short* ob;     // add_temb out (bf16)
    int K, N, nbx, KS, act;
};

__device__ __forceinline__ void run_xjob(const XJob xj, int bid, int tid,
                                         int nthr, float* AsRaw)
{
    if (xj.kind == 1) {
        float (*As)[128] = reinterpret_cast<float(*)[128]>(AsRaw);
        const int cb = bid % xj.nbx, kz = bid / xj.nbx;
        for (int i = tid; i < 4096; i += nthr) {
            const int r = i >> 7, k = i & 127;
            As[r][k] = xj.a[(size_t)r * xj.K + kz * 128 + k];
        }
        __syncthreads();
        if (tid < 256) {
            const int c = cb * 256 + tid;
            float acc[32];
            #pragma unroll
            for (int r = 0; r < 32; ++r) acc[r] = 0.f;
            const float* wrow = xj.w + (size_t)c * xj.K + kz * 128;
            for (int k4 = 0; k4 < 32; ++k4) {
                const float4 w4 = reinterpret_cast<const float4*>(wrow)[k4];
                #pragma unroll
                for (int r = 0; r < 32; ++r) {
                    const float4 a4 = *reinterpret_cast<const float4*>(&As[r][k4 * 4]);
                    acc[r] = fmaf(w4.x, a4.x, fmaf(w4.y, a4.y,
                              fmaf(w4.z, a4.z, fmaf(w4.w, a4.w, acc[r]))));
                }
            }
            float* pp = xj.o + ((size_t)kz * xj.N + c) * 32;
            #pragma unroll
            for (int r = 0; r < 32; ++r) pp[r] = acc[r];
        }
    } else if (xj.kind == 2) {
        if (tid < 256) {
            const int idx = bid * 256 + tid;
            const int r = idx & 31, c = idx >> 5;
            float s = 0.f;
            for (int kz = 0; kz < xj.KS; ++kz)
                s += xj.a[(size_t)kz * xj.N * 32 + idx];
            s += xj.w[c];
            if (xj.act == 2) s = s / (1.f + __expf(-s));
            xj.o[(size_t)r * xj.N + c] = s;
        }
    } else if (xj.kind == 3) {
        if (tid < 256) {
            const size_t i4 = (size_t)bid * 256 + tid;
            const size_t elem = i4 * 4;
            const int b = (int)(elem >> 18);
            const int c = (int)(elem & (CHN - 1));
            const float4 a = reinterpret_cast<const float4*>(xj.a)[i4];
            const float4 tv = *reinterpret_cast<const float4*>(xj.w + (size_t)b * CHN + c);
            ushort4 o;
            o.x = f2b(a.x + tv.x); o.y = f2b(a.y + tv.y);
            o.z = f2b(a.z + tv.z); o.w = f2b(a.w + tv.w);
            reinterpret_cast<ushort4*>(xj.ob)[i4] = o;
        }
    }
}

// ---------------------------------------------------------------------------
// cvt8: 6 weight matrices + log_seqs -> bf16, plus temb embedding (job 7).
// Weight slab layout unchanged from r14.
// ---------------------------------------------------------------------------
__global__ __launch_bounds__(256) void cvt8_kernel(
    const float* __restrict__ p0, const float* __restrict__ p1,
    const float* __restrict__ p2, const float* __restrict__ p3,
    const float* __restrict__ p4, const float* __restrict__ p5,
    unsigned short* __restrict__ y,
    const float* __restrict__ seqs, unsigned short* __restrict__ R1,
    const int* __restrict__ tt, float* __restrict__ T0)
{
    const int j = blockIdx.y;
    const int i = blockIdx.x * 256 + threadIdx.x;
    if (j < 6) {
        const float* x = j == 0 ? p0 : j == 1 ? p1 : j == 2 ? p2
                       : j == 3 ? p3 : j == 4 ? p4 : p5;
        const float4 v = reinterpret_cast<const float4*>(x)[i];
        ushort4 o;
        o.x = f2b(v.x); o.y = f2b(v.y); o.z = f2b(v.z); o.w = f2b(v.w);
        size_t dst4;
        if (j == 1)      dst4 = 131072 + i + (i >= 65536 ? 65536 : 0);
        else if (j == 2) dst4 = 131072 + 65536 + i + (i >= 65536 ? 65536 : 0);
        else             dst4 = (size_t)j * 131072 + i;
        reinterpret_cast<ushort4*>(y)[dst4] = o;
    } else if (j == 6) {
        #pragma unroll
        for (int t = 0; t < 16; ++t) {
            const int ii = t * 131072 + i;
            const float4 v = reinterpret_cast<const float4*>(seqs)[ii];
            ushort4 o;
            o.x = f2b(v.x); o.y = f2b(v.y); o.z = f2b(v.z); o.w = f2b(v.w);
            reinterpret_cast<ushort4*>(R1)[ii] = o;
        }
    } else {
        // temb embedding: BB*CHN = 16384 elems -> blocks 0..63
        if (blockIdx.x < 64) {
            const int idx = blockIdx.x * 256 + threadIdx.x;
            const int b = idx >> 9, jj0 = idx & 511;
            const float tv = (float)tt[b];
            const int jj = (jj0 < 256) ? jj0 : jj0 - 256;
            const float freq = __expf((float)jj * (-9.210340371976184f / 255.f));
            const float ang = tv * freq;
            T0[idx] = (jj0 < 256) ? sinf(ang) : cosf(ang);
        }
    }
}

// ---------------------------------------------------------------------------
// Row LayerNorm over CH=512 (eps=1e-8), bf16 input, f32 stats. Hosts xjobs.
// ---------------------------------------------------------------------------
__global__ __launch_bounds__(256) void ln_kernel(
    const unsigned short* __restrict__ x, const float* __restrict__ g,
    const float* __restrict__ b, float* __restrict__ yf,
    unsigned short* __restrict__ yb, int mainBlocks, XJob xj)
{
    __shared__ float red[8];
    __shared__ alignas(16) float lnAs[4096];
    if ((int)blockIdx.x >= mainBlocks) {
        run_xjob(xj, blockIdx.x - mainBlocks, threadIdx.x, 256, lnAs);
        return;
    }
    const int row = blockIdx.x;
    const int tid = threadIdx.x;
    const size_t base = (size_t)row * CHN;
    const ushort2 v2 = *reinterpret_cast<const ushort2*>(x + base + tid * 2);
    const float vx = b2f(v2.x), vy = b2f(v2.y);
    float s  = vx + vy;
    float ss = vx * vx + vy * vy;
    #pragma unroll
    for (int m = 1; m < 64; m <<= 1) {
        s  += __shfl_xor(s, m);
        ss += __shfl_xor(ss, m);
    }
    const int wave = tid >> 6;
    if ((tid & 63) == 0) { red[wave] = s; red[4 + wave] = ss; }
    __syncthreads();
    s  = red[0] + red[1] + red[2] + red[3];
    ss = red[4] + red[5] + red[6] + red[7];
    const float mean = s * (1.0f / CHN);
    const float var  = ss * (1.0f / CHN) - mean * mean;
    const float inv  = rsqrtf(var + 1e-8f);
    const int c = tid * 2;
    float ox = (vx - mean) * inv * g[c]     + b[c];
    float oy = (vy - mean) * inv * g[c + 1] + b[c + 1];
    if (yf) *reinterpret_cast<float2*>(yf + base + c) = make_float2(ox, oy);
    if (yb) {
        ushort2 ob; ob.x = f2b(ox); ob.y = f2b(oy);
        *reinterpret_cast<ushort2*>(yb + base + c) = ob;
    }
}

// ---------------------------------------------------------------------------
// bf16 MFMA GEMM body (depth-3, measured-best): 256x128 tile, BK=32,
// 8 waves (4x2). NBX = N/128 tiles. act: 0=none 1=relu 3=scale-by-0.125.
// ---------------------------------------------------------------------------
template <int NT, int NBX>
__device__ __forceinline__ void gemm_body(
    const unsigned short* __restrict__ A,
    const unsigned short* __restrict__ A2,
    const unsigned short* __restrict__ W, int ldw,
    const float* __restrict__ bias,
    const float* __restrict__ pos,
    const unsigned short* __restrict__ resb,
    float* __restrict__ outf,
    unsigned short* __restrict__ outb,
    unsigned short* __restrict__ outbt,
    int act, int bid,
    unsigned short* lA, unsigned short* lB)
{
    const int tid  = threadIdx.x;
    const int lane = tid & 63;
    const int wid  = tid >> 6;          // 0..7

    const int swz = (bid & 7) * (NBX * 8) + (bid >> 3);
    const int by = swz / NBX, bx = swz % NBX;
    const int bm = by * 256, bn = bx * 128;

    const int ia0 = wid * 2, ia1 = wid * 2 + 1;
    const int hiA0 = ia0 >> 2, rgA0 = ia0 & 3;
    const int hiA1 = ia1 >> 2, rgA1 = ia1 & 3;
    const int hiB = wid >> 1, rgB = wid & 1;

    const unsigned short* Ax = A2 ? A2 : A;
    const unsigned short* aS0  = A  + (size_t)(bm + rgA0 * 64 + lane) * 512 + hiA0 * 8;
    const unsigned short* aS1  = A  + (size_t)(bm + rgA1 * 64 + lane) * 512 + hiA1 * 8;
    const unsigned short* a2S0 = Ax + (size_t)(bm + rgA0 * 64 + lane) * 512 + hiA0 * 8;
    const unsigned short* a2S1 = Ax + (size_t)(bm + rgA1 * 64 + lane) * 512 + hiA1 * 8;
    const unsigned short* wS   = W + (size_t)(bn + rgB * 64 + lane) * ldw + hiB * 8;
    const int dA0 = (hiA0 * 256 + rgA0 * 64) * 8;
    const int dA1 = (hiA1 * 256 + rgA1 * 64) * 8;
    const int dB  = (hiB * 128 + rgB * 64) * 8;

    const int wr = wid >> 1, wc = wid & 1;
    const int fr = lane & 15;
    const int fq = lane >> 4;

    f32x4 acc[4][4];
    #pragma unroll
    for (int m = 0; m < 4; ++m)
        #pragma unroll
        for (int n = 0; n < 4; ++n)
            acc[m][n] = (f32x4){0.f, 0.f, 0.f, 0.f};

    #define MG_STAGE(buf, t)                                            \
        do {                                                            \
            const int k0 = ((t) & 15) * 32;                             \
            const unsigned short* s0 = ((t) < 16) ? aS0 : a2S0;         \
            const unsigned short* s1 = ((t) < 16) ? aS1 : a2S1;         \
            gl16(s0 + k0, &lA[(buf) * 8192 + dA0]);                     \
            gl16(s1 + k0, &lA[(buf) * 8192 + dA1]);                     \
            gl16(wS + (t) * 32, &lB[(buf) * 4096 + dB]);                \
        } while (0)

    MG_STAGE(0, 0);
    MG_STAGE(1, 1);

    #pragma unroll
    for (int t = 0; t < NT; ++t) {
        const int cur = t % 3;
        if (t + 2 < NT) {
            MG_STAGE((t + 2) % 3, t + 2);
            asm volatile("s_waitcnt vmcnt(6)" ::: "memory");
        } else if (t + 1 < NT) {
            asm volatile("s_waitcnt vmcnt(3)" ::: "memory");
        } else {
            asm volatile("s_waitcnt vmcnt(0)" ::: "memory");
        }
        __builtin_amdgcn_s_barrier();

        const unsigned short* pa = &lA[cur * 8192 + (fq * 256 + wr * 64 + fr) * 8];
        const unsigned short* pb = &lB[cur * 4096 + (fq * 128 + wc * 64 + fr) * 8];
        short8 aF[4], bF[4];
        #pragma unroll
        for (int m = 0; m < 4; ++m)
            aF[m] = *reinterpret_cast<const short8*>(pa + m * 128);
        #pragma unroll
        for (int n = 0; n < 4; ++n)
            bF[n] = *reinterpret_cast<const short8*>(pb + n * 128);
        asm volatile("s_waitcnt lgkmcnt(0)" ::: "memory");
        __builtin_amdgcn_s_barrier();

        __builtin_amdgcn_s_setprio(1);
        #pragma unroll
        for (int m = 0; m < 4; ++m)
            #pragma unroll
            for (int n = 0; n < 4; ++n)
                acc[m][n] = __builtin_amdgcn_mfma_f32_16x16x32_bf16(
                    aF[m], bF[n], acc[m][n], 0, 0, 0);
        __builtin_amdgcn_s_setprio(0);
    }
    #undef MG_STAGE

    const int row0 = bm + wr * 64, col0 = bn + wc * 64;
    #pragma unroll
    for (int m = 0; m < 4; ++m) {
        #pragma unroll
        for (int n = 0; n < 4; ++n) {
            const int col = col0 + n * 16 + fr;
            const float bia = bias ? bias[col] : 0.f;
            ushort4 o4;
            #pragma unroll
            for (int r = 0; r < 4; ++r) {
                const int row = row0 + m * 16 + fq * 4 + r;
                float v = acc[m][n][r] + bia;
                if (pos) v += pos[(size_t)(row & (LL - 1)) * CHN + col];
                if (act == 1) v = fmaxf(v, 0.f);
                else if (act == 3) v *= 0.125f;
                const size_t idx = (size_t)row * CHN + col;
                if (resb) v += b2f(resb[idx]);
                if (outf) outf[idx] = v;
                if (outb) outb[idx] = f2b(v);
                ((unsigned short*)&o4)[r] = f2b(v);
            }
            if (outbt) {
                const int rw = row0 + m * 16 + fq * 4;
                *reinterpret_cast<ushort4*>(
                    &outbt[((size_t)(rw >> 9) * 512 + col) * 512 + (rw & 511)]) = o4;
            }
        }
    }
}

// ---------------------------------------------------------------------------
// KV body: N=1024 GEMM over W_kv = [kw;vw], depth-3. Block-uniform epilogue
// split: bn<512 -> K (posK, KBb); bn>=512 -> V (posV, VTb transposed).
// ---------------------------------------------------------------------------
__device__ __forceinline__ void kv_body(
    const unsigned short* __restrict__ A,
    const unsigned short* __restrict__ Wkv,
    const float* __restrict__ kb, const float* __restrict__ vb,
    const float* __restrict__ posK, const float* __restrict__ posV,
    unsigned short* __restrict__ KBb, unsigned short* __restrict__ VTb,
    int bid, unsigned short* lA, unsigned short* lB)
{
    const int tid  = threadIdx.x;
    const int lane = tid & 63;
    const int wid  = tid >> 6;

    const int swz = (bid & 7) * 64 + (bid >> 3);   // 512 blocks
    const int by = swz >> 3, bx = swz & 7;
    const int bm = by * 256, bn = bx * 128;

    const int ia0 = wid * 2, ia1 = wid * 2 + 1;
    const int hiA0 = ia0 >> 2, rgA0 = ia0 & 3;
    const int hiA1 = ia1 >> 2, rgA1 = ia1 & 3;
    const int hiB = wid >> 1, rgB = wid & 1;

    const unsigned short* aS0 = A + (size_t)(bm + rgA0 * 64 + lane) * 512 + hiA0 * 8;
    const unsigned short* aS1 = A + (size_t)(bm + rgA1 * 64 + lane) * 512 + hiA1 * 8;
    const unsigned short* wS  = Wkv + (size_t)(bn + rgB * 64 + lane) * 512 + hiB * 8;
    const int dA0 = (hiA0 * 256 + rgA0 * 64) * 8;
    const int dA1 = (hiA1 * 256 + rgA1 * 64) * 8;
    const int dB  = (hiB * 128 + rgB * 64) * 8;

    const int wr = wid >> 1, wc = wid & 1;
    const int fr = lane & 15;
    const int fq = lane >> 4;

    f32x4 acc[4][4];
    #pragma unroll
    for (int m = 0; m < 4; ++m)
        #pragma unroll
        for (int n = 0; n < 4; ++n)
            acc[m][n] = (f32x4){0.f, 0.f, 0.f, 0.f};

    #define KV_STAGE(buf, t)                                            \
        do {                                                            \
            const int k0 = (t) * 32;                                    \
            gl16(aS0 + k0, &lA[(buf) * 8192 + dA0]);                    \
            gl16(aS1 + k0, &lA[(buf) * 8192 + dA1]);                    \
            gl16(wS + k0, &lB[(buf) * 4096 + dB]);                      \
        } while (0)

    KV_STAGE(0, 0);
    KV_STAGE(1, 1);

    #pragma unroll
    for (int t = 0; t < 16; ++t) {
        const int cur = t % 3;
        if (t + 2 < 16) {
            KV_STAGE((t + 2) % 3, t + 2);
            asm volatile("s_waitcnt vmcnt(6)" ::: "memory");
        } else if (t + 1 < 16) {
            asm volatile("s_waitcnt vmcnt(3)" ::: "memory");
        } else {
            asm volatile("s_waitcnt vmcnt(0)" ::: "memory");
        }
        __builtin_amdgcn_s_barrier();

        const unsigned short* pa = &lA[cur * 8192 + (fq * 256 + wr * 64 + fr) * 8];
        const unsigned short* pb = &lB[cur * 4096 + (fq * 128 + wc * 64 + fr) * 8];
        short8 aF[4], bF[4];
        #pragma unroll
        for (int m = 0; m < 4; ++m)
            aF[m] = *reinterpret_cast<const short8*>(pa + m * 128);
        #pragma unroll
        for (int n = 0; n < 4; ++n)
            bF[n] = *reinterpret_cast<const short8*>(pb + n * 128);
        asm volatile("s_waitcnt lgkmcnt(0)" ::: "memory");
        __builtin_amdgcn_s_barrier();

        __builtin_amdgcn_s_setprio(1);
        #pragma unroll
        for (int m = 0; m < 4; ++m)
            #pragma unroll
            for (int n = 0; n < 4; ++n)
                acc[m][n] = __builtin_amdgcn_mfma_f32_16x16x32_bf16(
                    aF[m], bF[n], acc[m][n], 0, 0, 0);
        __builtin_amdgcn_s_setprio(0);
    }
    #undef KV_STAGE

    const int row0 = bm + wr * 64;
    if (bn < 512) {
        const int col0 = bn + wc * 64;
        #pragma unroll
        for (int m = 0; m < 4; ++m) {
            #pragma unroll
            for (int n = 0; n < 4; ++n) {
                const int col = col0 + n * 16 + fr;
                const float bia = kb[col];
                #pragma unroll
                for (int r = 0; r < 4; ++r) {
                    const int row = row0 + m * 16 + fq * 4 + r;
                    float v = acc[m][n][r] + bia
                            + posK[(size_t)(row & (LL - 1)) * CHN + col];
                    KBb[(size_t)row * CHN + col] = f2b(v);
                }
            }
        }
    } else {
        const int vcol0 = (bn - 512) + wc * 64;
        #pragma unroll
        for (int m = 0; m < 4; ++m) {
            #pragma unroll
            for (int n = 0; n < 4; ++n) {
                const int vcol = vcol0 + n * 16 + fr;
                const float bia = vb[vcol];
                ushort4 o4;
                #pragma unroll
                for (int r = 0; r < 4; ++r) {
                    const int row = row0 + m * 16 + fq * 4 + r;
                    float v = acc[m][n][r] + bia
                            + posV[(size_t)(row & (LL - 1)) * CHN + vcol];
                    ((unsigned short*)&o4)[r] = f2b(v);
                }
                const int rw = row0 + m * 16 + fq * 4;
                *reinterpret_cast<ushort4*>(
                    &VTb[((size_t)(rw >> 9) * 512 + vcol) * 512 + (rw & 511)]) = o4;
            }
        }
    }
}

__global__ __launch_bounds__(512) void mgemm_kernel(
    const unsigned short* __restrict__ A,
    const unsigned short* __restrict__ W, int ldw,
    const float* __restrict__ bias,
    const float* __restrict__ pos,
    const unsigned short* __restrict__ resb,
    float* __restrict__ outf,
    unsigned short* __restrict__ outb,
    unsigned short* __restrict__ outbt,
    int act, int mainBlocks, XJob xj)
{
    __shared__ alignas(16) unsigned short lA[3 * 8192];
    __shared__ alignas(16) unsigned short lB[3 * 4096];
    if ((int)blockIdx.x >= mainBlocks) {
        run_xjob(xj, blockIdx.x - mainBlocks, threadIdx.x, 512, (float*)lA);
        return;
    }
    gemm_body<16, 4>(A, nullptr, W, ldw, bias, pos, resb, outf, outb, outbt, act,
                     blockIdx.x, lA, lB);
}

// Fused Q + KV: blocks 0-255 = Q GEMM, 256-767 = KV GEMM, >=768 = xjob.
__global__ __launch_bounds__(512) void qkv2_kernel(
    const unsigned short* __restrict__ qinb, const unsigned short* __restrict__ curb,
    const unsigned short* __restrict__ Wq, const unsigned short* __restrict__ Wkv,
    const float* __restrict__ qb, const float* __restrict__ kb,
    const float* __restrict__ vb,
    const float* __restrict__ posK, const float* __restrict__ posV,
    unsigned short* __restrict__ QBb, unsigned short* __restrict__ KBb,
    unsigned short* __restrict__ VTb, XJob xj)
{
    __shared__ alignas(16) unsigned short lA[3 * 8192];
    __shared__ alignas(16) unsigned short lB[3 * 4096];
    if (blockIdx.x >= 768) {
        run_xjob(xj, blockIdx.x - 768, threadIdx.x, 512, (float*)lA);
        return;
    }
    if (blockIdx.x < 256) {
        gemm_body<16, 4>(qinb, nullptr, Wq, 512, qb, nullptr, nullptr,
                         nullptr, QBb, nullptr, 3, blockIdx.x, lA, lB);
    } else {
        kv_body(curb, Wkv, kb, vb, posK, posV, KBb, VTb, blockIdx.x - 256, lA, lB);
    }
}

// Decoder fused: dec = [log_feats | x_t] @ decw^T + decb  (K=1024, two A sources)
__global__ __launch_bounds__(512) void dec_kernel(
    const unsigned short* __restrict__ R0b, const unsigned short* __restrict__ R1b,
    const unsigned short* __restrict__ Wd, const float* __restrict__ decb,
    float* __restrict__ dec)
{
    __shared__ alignas(16) unsigned short lA[3 * 8192];
    __shared__ alignas(16) unsigned short lB[3 * 4096];
    gemm_body<32, 4>(R0b, R1b, Wd, 1024, decb, nullptr, nullptr, dec, nullptr,
                     nullptr, 0, blockIdx.x, lA, lB);
}

// ---------------------------------------------------------------------------
// MFMA causal flash attention, paired q-tiles on PARALLEL wave-groups
// (r18 measured-best). 512 threads / 8 waves; group 0 -> qtB, group 1 -> qtA.
// ---------------------------------------------------------------------------
__global__ __launch_bounds__(512) void mattn_kernel(
    const unsigned short* __restrict__ Q, const unsigned short* __restrict__ K,
    const unsigned short* __restrict__ VT, const unsigned short* __restrict__ Qin,
    unsigned short* __restrict__ Sout)
{
    __shared__ alignas(16) unsigned short kT[2][4096];
    __shared__ alignas(16) unsigned short vT[2][4096];
    __shared__ unsigned short pl[8][1024];

    const int pr = blockIdx.x;          // 0..3
    const int qtA = pr, qtB = 7 - pr;
    const int h  = blockIdx.y;
    const int b  = blockIdx.z;
    const int tid = threadIdx.x, lane = tid & 63, wid = tid >> 6;
    const int wg = wid >> 2;
    const int wl = wid & 3;
    const int fr = lane & 15, fq = lane >> 4;
    const int hc = h * HDD;

    const int rs = tid >> 3, js = tid & 7, ds = ((js ^ (rs & 7)) << 3);
    const unsigned short* kS = K + (size_t)b * LL * CHN + (size_t)rs * CHN + hc + ds;
    const unsigned short* vS = VT + ((size_t)(b * NHH + h) * 64 + rs) * 512 + ds;

    #define AT_STAGE(buf, ch)                                              \
        do {                                                               \
            const int o = (ch) * 64;                                       \
            gl16(kS + (size_t)o * CHN, &kT[buf][wid * 512]);               \
            gl16(vS + o, &vT[buf][wid * 512]);                             \
        } while (0)

    const int myQt = wg ? qtA : qtB;
    const size_t qrow = (size_t)b * LL + myQt * 64 + wl * 16 + fr;
    short8 qf[2];
    qf[0] = *reinterpret_cast<const short8*>(Q + qrow * CHN + hc + fq * 8);
    qf[1] = *reinterpret_cast<const short8*>(Q + qrow * CHN + hc + 32 + fq * 8);

    f32x4 oacc[4];
    float lrow[4];
    #pragma unroll
    for (int n = 0; n < 4; ++n) oacc[n] = (f32x4){0.f, 0.f, 0.f, 0.f};
    #pragma unroll
    for (int r = 0; r < 4; ++r) lrow[r] = 0.f;

    AT_STAGE(0, 0);
    __syncthreads();

    for (int ch = 0; ch <= qtB; ++ch) {
        const int cur = ch & 1;
        if (ch < qtB) AT_STAGE(cur ^ 1, ch + 1);

        if (ch <= myQt) {
            f32x4 sacc[4];
            #pragma unroll
            for (int n = 0; n < 4; ++n) sacc[n] = (f32x4){0.f, 0.f, 0.f, 0.f};
            __builtin_amdgcn_s_setprio(1);
            #pragma unroll
            for (int kk = 0; kk < 2; ++kk) {
                #pragma unroll
                for (int n = 0; n < 4; ++n) {
                    const short8 kf = *reinterpret_cast<const short8*>(
                        &kT[cur][SWZ(n * 16 + fr, kk * 32 + fq * 8)]);
                    sacc[n] = __builtin_amdgcn_mfma_f32_16x16x32_bf16(
                        qf[kk], kf, sacc[n], 0, 0, 0);
                }
            }
            __builtin_amdgcn_s_setprio(0);

            const bool diag = (ch == myQt);
            #pragma unroll
            for (int r = 0; r < 4; ++r) {
                float sv[4];
                #pragma unroll
                for (int n = 0; n < 4; ++n) {
                    float v = sacc[n][r];
                    if (diag && (n * 16 + fr > wl * 16 + fq * 4 + r)) v = -1e30f;
                    sv[n] = __expf(v);
                }
                float ps = (sv[0] + sv[1]) + (sv[2] + sv[3]);
                ps += __shfl_xor(ps, 1);
                ps += __shfl_xor(ps, 2);
                ps += __shfl_xor(ps, 4);
                ps += __shfl_xor(ps, 8);
                lrow[r] += ps;
                #pragma unroll
                for (int n = 0; n < 4; ++n)
                    pl[wid][SWZ(fq * 4 + r, n * 16 + fr)] = f2b(sv[n]);
            }

            __builtin_amdgcn_s_setprio(1);
            #pragma unroll
            for (int kk = 0; kk < 2; ++kk) {
                const short8 pa = *reinterpret_cast<const short8*>(
                    &pl[wid][SWZ(fr, kk * 32 + fq * 8)]);
                #pragma unroll
                for (int n = 0; n < 4; ++n) {
                    const short8 vf = *reinterpret_cast<const short8*>(
                        &vT[cur][SWZ(n * 16 + fr, kk * 32 + fq * 8)]);
                    oacc[n] = __builtin_amdgcn_mfma_f32_16x16x32_bf16(
                        pa, vf, oacc[n], 0, 0, 0);
                }
            }
            __builtin_amdgcn_s_setprio(0);
        }

        __syncthreads();
    }
    #undef AT_STAGE

    const size_t orow0 = (size_t)b * LL + myQt * 64 + wl * 16 + fq * 4;
    #pragma unroll
    for (int r = 0; r < 4; ++r) {
        const float inv = 1.f / lrow[r];
        const size_t rowidx = (orow0 + r) * CHN + hc;
        #pragma unroll
        for (int n = 0; n < 4; ++n) {
            const int d = n * 16 + fr;
            Sout[rowidx + d] = f2b(oacc[n][r] * inv + b2f(Qin[rowidx + d]));
        }
    }
}

// ---------------------------------------------------------------------------
extern "C" void kernel_launch(void* const* d_in, const int* in_sizes, int n_in,
                              void* d_out, int out_size, void* d_ws, size_t ws_size,
                              hipStream_t stream)
{
    (void)in_sizes; (void)n_in; (void)out_size; (void)ws_size;
    const float* log_seqs = (const float*)d_in[0];
    const float* seqs_nxt = (const float*)d_in[1];
    const int*   tt       = (const int*)d_in[2];
    const float* qw  = (const float*)d_in[3];
    const float* qb  = (const float*)d_in[4];
    const float* kw  = (const float*)d_in[5];
    const float* kb  = (const float*)d_in[6];
    const float* vw  = (const float*)d_in[7];
    const float* vb  = (const float*)d_in[8];
    const float* ln1g = (const float*)d_in[9];
    const float* ln1b = (const float*)d_in[10];
    const float* ln2g = (const float*)d_in[11];
    const float* ln2b = (const float*)d_in[12];
    const float* c1w = (const float*)d_in[13];
    const float* c1b = (const float*)d_in[14];
    const float* c2w = (const float*)d_in[15];
    const float* c2b = (const float*)d_in[16];
    const float* posK = (const float*)d_in[17];
    const float* posV = (const float*)d_in[18];
    const float* lng = (const float*)d_in[19];
    const float* lnb = (const float*)d_in[20];
    const float* tw0 = (const float*)d_in[21];
    const float* tb0 = (const float*)d_in[22];
    const float* tw1 = (const float*)d_in[23];
    const float* tb1 = (const float*)d_in[24];
    const float* tw2 = (const float*)d_in[25];
    const float* tb2 = (const float*)d_in[26];
    const float* decw = (const float*)d_in[27];
    const float* decb = (const float*)d_in[28];

    const size_t SZ = (size_t)BB * LL * CHN;  // 8388608
    const int M = BB * LL;                    // 16384
    float* out = (float*)d_out;
    float* log_feats = out;
    float* dec = out + SZ;
    unsigned short* QBb = (unsigned short*)dec;        // Q bf16 until decoder
    unsigned short* VTb = (unsigned short*)log_feats;  // V^T bf16 until final LN

    float* ws = (float*)d_ws;
    unsigned short* SB = (unsigned short*)ws;                 // residual stream bf16
    float* P = ws + SZ / 2;                                   // split-K partials
    unsigned short* KBb = (unsigned short*)(ws + SZ);         // K buf; later x_t
    unsigned short* R0  = (unsigned short*)(ws + SZ + SZ / 2);
    unsigned short* R1  = (unsigned short*)(ws + 2 * SZ);
    unsigned short* WBu = (unsigned short*)(ws + 2 * SZ + SZ / 2);  // 3145728 bf16
    float* T0 = ws + 2 * SZ + SZ / 2 + 1572864;
    float* T1 = T0 + 32 * CHN;
    float* T2 = T1 + 32 * 2048;
    float* T3 = T2 + 32 * 2048;
    unsigned short* XT = KBb;   // x_t bf16 (KBb dead after L1 mattn)

    const size_t WQ = 0, WKV = 524288, WC1 = 1572864,
                 WC2 = 2097152, WDEC = 2621440;

    XJob xnone; xnone.kind = 0;
    xnone.a = nullptr; xnone.w = nullptr; xnone.o = nullptr; xnone.ob = nullptr;
    xnone.K = 0; xnone.N = 0; xnone.nbx = 1; xnone.KS = 0; xnone.act = 0;

    auto mkgemm = [&](const float* A, const float* W, float* Pp, int K, int N) {
        XJob x = xnone; x.kind = 1; x.a = A; x.w = W; x.o = Pp;
        x.K = K; x.N = N; x.nbx = N / 256;
        return x;
    };
    auto mkred = [&](const float* Pp, const float* bias, float* o,
                     int KS, int N, int act) {
        XJob x = xnone; x.kind = 2; x.a = Pp; x.w = bias; x.o = o;
        x.KS = KS; x.N = N; x.act = act;
        return x;
    };

    // conversions + temb embedding, one launch
    cvt8_kernel<<<dim3(512, 8), 256, 0, stream>>>(qw, kw, vw, c1w, c2w, decw, WBu,
                                                  log_seqs, R1, tt, T0);

    for (int i = 0; i < 2; ++i) {
        const size_t wo = (size_t)i * 262144;
        const size_t bo = (size_t)i * CHN;

        // ln1 (+ L0: skgemm1 T0@tw0 -> P; L1: skreduce3 P -> T3)
        XJob xln1 = (i == 0) ? mkgemm(T0, tw0, P, 512, 2048)
                             : mkred(P, tb2, T3, 16, 512, 0);
        const int xln1n = (i == 0) ? (2048 / 256) * (512 / 128) : (512 * 32) / 256;
        ln_kernel<<<M + xln1n, 256, 0, stream>>>(R1, ln1g + bo, ln1b + bo,
                                                 nullptr, R0, M, xln1);

        // qkv2 (+ L0: skreduce1 P -> T1)
        XJob xqkv = (i == 0) ? mkred(P, tb0, T1, 4, 2048, 2) : xnone;
        const int xqkvn = (i == 0) ? (2048 * 32) / 256 : 0;
        qkv2_kernel<<<768 + xqkvn, 512, 0, stream>>>(
            R0, R1, WBu + WQ + wo, WBu + WKV + (size_t)i * 524288,
            qb + bo, kb + bo, vb + bo, posK, posV, QBb, KBb, VTb, xqkv);

        mattn_kernel<<<dim3(4, NHH, BB), 512, 0, stream>>>(QBb, KBb, VTb, R0, SB);

        // ln2 (+ L0: skgemm2 T1@tw1 -> P; L1: add_temb seqs_nxt + T3 -> XT)
        XJob xln2;
        int xln2n;
        if (i == 0) {
            xln2 = mkgemm(T1, tw1, P, 2048, 2048);
            xln2n = (2048 / 256) * (2048 / 128);
        } else {
            xln2 = xnone; xln2.kind = 3; xln2.a = seqs_nxt; xln2.w = T3; xln2.ob = XT;
            xln2n = (int)(SZ / 4 / 256);
        }
        ln_kernel<<<M + xln2n, 256, 0, stream>>>(SB, ln2g + bo, ln2b + bo,
                                                 nullptr, SB, M, xln2);

        // c1 (+ L0: skreduce2 P -> T2)
        XJob xc1 = (i == 0) ? mkred(P, tb1, T2, 16, 2048, 2) : xnone;
        const int xc1n = (i == 0) ? (2048 * 32) / 256 : 0;
        mgemm_kernel<<<256 + xc1n, 512, 0, stream>>>(
            SB, WBu + WC1 + wo, 512, c1b + bo, nullptr, nullptr,
            nullptr, R0, nullptr, 1, 256, xc1);

        // c2 (+ L0: skgemm3 T2@tw2 -> P)
        XJob xc2 = (i == 0) ? mkgemm(T2, tw2, P, 2048, 512) : xnone;
        const int xc2n = (i == 0) ? (512 / 256) * (2048 / 128) : 0;
        mgemm_kernel<<<256 + xc2n, 512, 0, stream>>>(
            R0, WBu + WC2 + wo, 512, c2b + bo, nullptr, SB,
            nullptr, R1, nullptr, 0, 256, xc2);
    }

    ln_kernel<<<M, 256, 0, stream>>>(R1, lng, lnb, log_feats, R0, M, xnone);

    dec_kernel<<<256, 512, 0, stream>>>(R0, XT, WBu + WDEC, decb, dec);
}